// Round 1
// baseline (704.734 us; speedup 1.0000x reference)
//
#include <hip/hip_runtime.h>
#include <hip/hip_bf16.h>

#define SEQLEN 2048
#define DMODEL 1024
#define INNER  2048
#define DSTATE 16
#define DTRANK 64
#define NPROJ  96   // DTRANK + 2*DSTATE
#define CHUNK  64
#define NCH    32   // SEQLEN / CHUNK

__device__ __forceinline__ float softplusf(float x) {
    return (x > 20.f) ? x : log1pf(__expf(x));
}

// C = A @ B^T  (A: MxK row-major lda, B: NxK row-major ldb, C: MxN row-major ldc)
// EPI==1: C = softplus(acc + bias[col])
// split-K via blockIdx.z: k-range [z*kspan, z*kspan+kspan), C += z*zCstride
template<int BM, int BN, int BK, int TM, int TN, int EPI>
__global__ __launch_bounds__(256)
void gemm_abT(const float* __restrict__ A, int lda,
              const float* __restrict__ B, int ldb,
              float* __restrict__ C, int ldc, long long zCstride,
              int M, int N, int K, int kspan,
              const float* __restrict__ bias)
{
    constexpr int PAD = 4;
    __shared__ float As[BK][BM + PAD];
    __shared__ float Bs[BK][BN + PAD];

    const int tid  = threadIdx.x;
    const int row0 = blockIdx.y * BM;
    const int col0 = blockIdx.x * BN;
    const int kstart = blockIdx.z * kspan;
    const int kend   = min(K, kstart + kspan);
    C += (long long)blockIdx.z * zCstride;

    constexpr int NX = BN / TN;     // threads along N
    const int tx = tid % NX;
    const int ty = tid / NX;

    float acc[TM][TN];
#pragma unroll
    for (int i = 0; i < TM; ++i)
#pragma unroll
        for (int j = 0; j < TN; ++j) acc[i][j] = 0.f;

    constexpr int KV = BK / 4;              // float4 slots per row
    constexpr int ROWS_PER_PASS = 256 / KV; // rows staged per pass
    const int ak = (tid % KV) * 4;
    const int amBase = tid / KV;

    for (int kt = kstart; kt < kend; kt += BK) {
#pragma unroll
        for (int m = amBase; m < BM; m += ROWS_PER_PASS) {
            float4 v = *(const float4*)&A[(long long)(row0 + m) * lda + kt + ak];
            As[ak + 0][m] = v.x; As[ak + 1][m] = v.y;
            As[ak + 2][m] = v.z; As[ak + 3][m] = v.w;
        }
#pragma unroll
        for (int n = amBase; n < BN; n += ROWS_PER_PASS) {
            int gn = col0 + n;
            float4 v = make_float4(0.f, 0.f, 0.f, 0.f);
            if (gn < N) v = *(const float4*)&B[(long long)gn * ldb + kt + ak];
            Bs[ak + 0][n] = v.x; Bs[ak + 1][n] = v.y;
            Bs[ak + 2][n] = v.z; Bs[ak + 3][n] = v.w;
        }
        __syncthreads();
#pragma unroll
        for (int kk = 0; kk < BK; ++kk) {
            float a[TM], b[TN];
#pragma unroll
            for (int i = 0; i < TM; i += 4)
                *(float4*)&a[i] = *(const float4*)&As[kk][ty * TM + i];
#pragma unroll
            for (int j = 0; j < TN; j += 4)
                *(float4*)&b[j] = *(const float4*)&Bs[kk][tx * TN + j];
#pragma unroll
            for (int i = 0; i < TM; ++i)
#pragma unroll
                for (int j = 0; j < TN; ++j)
                    acc[i][j] = fmaf(a[i], b[j], acc[i][j]);
        }
        __syncthreads();
    }

#pragma unroll
    for (int i = 0; i < TM; ++i) {
        int row = row0 + ty * TM + i;
#pragma unroll
        for (int j = 0; j < TN; ++j) {
            int col = col0 + tx * TN + j;
            if (col < N) {
                float v = acc[i][j];
                if (EPI == 1) v = softplusf(v + bias[col]);
                C[(long long)row * ldc + col] = v;
            }
        }
    }
}

// u[l][d] = silu( sum_j conv_w[d][j] * proj[l-3+j][d] + conv_b[d] )
__global__ __launch_bounds__(256)
void conv_silu_kernel(const float* __restrict__ xz, const float* __restrict__ cw,
                      const float* __restrict__ cb, float* __restrict__ u)
{
    int i = blockIdx.x * 256 + threadIdx.x;   // i < SEQLEN*INNER
    int l = i >> 11;
    int d = i & (INNER - 1);
    float acc = cb[d];
#pragma unroll
    for (int j = 0; j < 4; ++j) {
        int ls = l - 3 + j;
        if (ls >= 0)
            acc = fmaf(cw[d * 4 + j], xz[(long long)ls * 4096 + d], acc);
    }
    u[i] = acc / (1.f + __expf(-acc));
}

// projt[i] = sum_z part[z][i]
__global__ __launch_bounds__(256)
void reduce_part(const float* __restrict__ part, float* __restrict__ projt)
{
    int i = blockIdx.x * 256 + threadIdx.x;   // i < SEQLEN*NPROJ
    float s = 0.f;
#pragma unroll
    for (int z = 0; z < 8; ++z) s += part[(long long)z * SEQLEN * NPROJ + i];
    projt[i] = s;
}

// Phase 1: local chunk scans from h0=0 -> chunk-final states + per-chunk delta sums
__global__ __launch_bounds__(256)
void scan_phase1(const float* __restrict__ delta, const float* __restrict__ u,
                 const float* __restrict__ projt, const float* __restrict__ A_log,
                 float* __restrict__ Sloc, float* __restrict__ sumd)
{
    __shared__ float BC[CHUNK][32];
    const int d  = blockIdx.x * 256 + threadIdx.x;
    const int c  = blockIdx.y;
    const int l0 = c * CHUNK;
    for (int i = threadIdx.x; i < CHUNK * 32; i += 256) {
        int l = i >> 5, j = i & 31;
        BC[l][j] = projt[(l0 + l) * NPROJ + DTRANK + j];
    }
    __syncthreads();

    float A2[DSTATE];
#pragma unroll
    for (int n = 0; n < DSTATE; ++n)
        A2[n] = -__expf(A_log[d * DSTATE + n]) * 1.4426950408889634f;

    float h[DSTATE];
#pragma unroll
    for (int n = 0; n < DSTATE; ++n) h[n] = 0.f;
    float sd = 0.f;

    for (int t = 0; t < CHUNK; ++t) {
        int l = l0 + t;
        float dl = delta[l * INNER + d];
        float ul = u[l * INNER + d];
        float du = dl * ul;
        sd += dl;
#pragma unroll
        for (int n = 0; n < DSTATE; ++n) {
            float dA = exp2f(dl * A2[n]);
            h[n] = fmaf(dA, h[n], du * BC[t][n]);
        }
    }
#pragma unroll
    for (int n = 0; n < DSTATE; ++n)
        Sloc[((long long)c * INNER + d) * DSTATE + n] = h[n];
    sumd[c * INNER + d] = sd;
}

// Phase 2: combine chunk states sequentially -> initial state per chunk
__global__ __launch_bounds__(256)
void scan_phase2(const float* __restrict__ Sloc, const float* __restrict__ sumd,
                 const float* __restrict__ A_log, float* __restrict__ Hinit)
{
    int i = blockIdx.x * 256 + threadIdx.x;   // i < INNER*DSTATE
    int d = i >> 4;
    float A2 = -__expf(A_log[i]) * 1.4426950408889634f;
    float H = 0.f;
#pragma unroll
    for (int c = 0; c < NCH; ++c) {
        Hinit[(long long)c * INNER * DSTATE + i] = H;
        float P = exp2f(A2 * sumd[c * INNER + d]);
        H = fmaf(P, H, Sloc[(long long)c * INNER * DSTATE + i]);
    }
}

// Phase 3: re-scan with correct init, y = sum_n h*C; fused epilogue:
// y = (y + D*u) * silu(gate); write into proj half of xz
__global__ __launch_bounds__(256)
void scan_phase3(const float* __restrict__ delta, const float* __restrict__ u,
                 const float* __restrict__ projt, const float* __restrict__ A_log,
                 const float* __restrict__ Hinit, float* __restrict__ xz,
                 const float* __restrict__ D_skip)
{
    __shared__ float BC[CHUNK][32];
    const int d  = blockIdx.x * 256 + threadIdx.x;
    const int c  = blockIdx.y;
    const int l0 = c * CHUNK;
    for (int i = threadIdx.x; i < CHUNK * 32; i += 256) {
        int l = i >> 5, j = i & 31;
        BC[l][j] = projt[(l0 + l) * NPROJ + DTRANK + j];
    }
    __syncthreads();

    float A2[DSTATE];
#pragma unroll
    for (int n = 0; n < DSTATE; ++n)
        A2[n] = -__expf(A_log[d * DSTATE + n]) * 1.4426950408889634f;

    float h[DSTATE];
#pragma unroll
    for (int n = 0; n < DSTATE; ++n)
        h[n] = Hinit[((long long)c * INNER + d) * DSTATE + n];
    const float Dd = D_skip[d];

    for (int t = 0; t < CHUNK; ++t) {
        int l = l0 + t;
        float dl = delta[l * INNER + d];
        float ul = u[l * INNER + d];
        float du = dl * ul;
        float y = 0.f;
#pragma unroll
        for (int n = 0; n < DSTATE; ++n) {
            float dA = exp2f(dl * A2[n]);
            h[n] = fmaf(dA, h[n], du * BC[t][n]);
            y = fmaf(h[n], BC[t][16 + n], y);
        }
        float yv = fmaf(Dd, ul, y);
        float g = xz[(long long)l * 4096 + 2048 + d];
        float sg = g / (1.f + __expf(-g));
        xz[(long long)l * 4096 + d] = yv * sg;
    }
}

extern "C" void kernel_launch(void* const* d_in, const int* in_sizes, int n_in,
                              void* d_out, int out_size, void* d_ws, size_t ws_size,
                              hipStream_t stream)
{
    const float* hidden  = (const float*)d_in[0];
    const float* W_in    = (const float*)d_in[1];
    const float* conv_w  = (const float*)d_in[2];
    const float* conv_b  = (const float*)d_in[3];
    const float* W_x     = (const float*)d_in[4];
    const float* W_dt    = (const float*)d_in[5];
    const float* dt_bias = (const float*)d_in[6];
    const float* A_log   = (const float*)d_in[7];
    const float* D_skip  = (const float*)d_in[8];
    const float* W_out   = (const float*)d_in[9];
    float* out = (float*)d_out;

    char* p = (char*)d_ws;
    float* xz    = (float*)p; p += (size_t)SEQLEN * 4096 * 4;        // 33.5MB (proj|gate; proj later overwritten by y)
    float* u     = (float*)p; p += (size_t)SEQLEN * INNER * 4;       // 16.8MB
    float* delta = (float*)p; p += (size_t)SEQLEN * INNER * 4;       // 16.8MB
    float* projt = (float*)p; p += (size_t)SEQLEN * NPROJ * 4;       // 0.8MB
    float* part  = (float*)p; p += (size_t)8 * SEQLEN * NPROJ * 4;   // 6.3MB
    float* Sloc  = (float*)p; p += (size_t)NCH * INNER * DSTATE * 4; // 4.2MB
    float* sumd  = (float*)p; p += (size_t)NCH * INNER * 4;          // 0.25MB
    float* Hinit = (float*)p; p += (size_t)NCH * INNER * DSTATE * 4; // 4.2MB

    // 1. xz = hidden @ W_in^T   (2048 x 4096, K=1024)
    gemm_abT<128,128,16,8,8,0><<<dim3(32,16,1),256,0,stream>>>(
        hidden, DMODEL, W_in, DMODEL, xz, 4096, 0, SEQLEN, 4096, DMODEL, DMODEL, nullptr);

    // 2. u = silu(causal depthwise conv(proj) + b)
    conv_silu_kernel<<<(SEQLEN * INNER) / 256, 256, 0, stream>>>(xz, conv_w, conv_b, u);

    // 3. projt = u @ W_x^T  (2048 x 96, K=2048) split-K 8-way + reduce
    gemm_abT<128,128,16,8,8,0><<<dim3(1,16,8),256,0,stream>>>(
        u, INNER, W_x, INNER, part, NPROJ, (long long)SEQLEN * NPROJ,
        SEQLEN, NPROJ, INNER, INNER / 8, nullptr);
    reduce_part<<<(SEQLEN * NPROJ) / 256, 256, 0, stream>>>(part, projt);

    // 4. delta = softplus(dt_lr @ W_dt^T + dt_bias)  (2048 x 2048, K=64)
    gemm_abT<128,128,16,8,8,1><<<dim3(16,16,1),256,0,stream>>>(
        projt, NPROJ, W_dt, DTRANK, delta, INNER, 0, SEQLEN, INNER, DTRANK, DTRANK, dt_bias);

    // 5-7. chunked selective scan + fused gated epilogue (y written over proj half of xz)
    scan_phase1<<<dim3(INNER / 256, NCH), 256, 0, stream>>>(delta, u, projt, A_log, Sloc, sumd);
    scan_phase2<<<(INNER * DSTATE) / 256, 256, 0, stream>>>(Sloc, sumd, A_log, Hinit);
    scan_phase3<<<dim3(INNER / 256, NCH), 256, 0, stream>>>(delta, u, projt, A_log, Hinit, xz, D_skip);

    // 8. out = y @ W_out^T  (2048 x 1024, K=2048)
    gemm_abT<128,64,16,8,4,0><<<dim3(16,16,1),256,0,stream>>>(
        xz, 4096, W_out, INNER, out, DMODEL, 0, SEQLEN, DMODEL, INNER, INNER, nullptr);
}

// Round 2
// 317.605 us; speedup vs baseline: 2.2189x; 2.2189x over previous
//
#include <hip/hip_runtime.h>
#include <hip/hip_bf16.h>

#define SEQLEN 2048
#define DMODEL 1024
#define INNER  2048
#define DSTATE 16
#define DTRANK 64
#define NPROJ  96   // DTRANK + 2*DSTATE
#define CHUNK  64
#define NCH    32   // SEQLEN / CHUNK

typedef __attribute__((ext_vector_type(8))) short bf16x8;
typedef __attribute__((ext_vector_type(4))) float f32x4;

__device__ __forceinline__ float softplusf(float x) {
    return (x > 20.f) ? x : log1pf(__expf(x));
}

// fp32 -> bf16 round-to-nearest-even (finite inputs)
__device__ __forceinline__ unsigned short f2bf(float x) {
    unsigned u = __float_as_uint(x);
    unsigned r = (u + 0x7FFF + ((u >> 16) & 1)) >> 16;
    return (unsigned short)r;
}

__device__ __forceinline__ void gload_lds16(const void* g, void* l) {
    __builtin_amdgcn_global_load_lds(
        (__attribute__((address_space(1))) const unsigned int*)g,
        (__attribute__((address_space(3))) unsigned int*)l,
        16, 0, 0);
}

// elementwise fp32 -> bf16, 8 elems/thread
__global__ __launch_bounds__(256)
void cvt_f32_bf16(const float* __restrict__ in, unsigned short* __restrict__ out, int n8)
{
    int i = blockIdx.x * 256 + threadIdx.x;
    if (i >= n8) return;
    float4 a = ((const float4*)in)[2 * i];
    float4 b = ((const float4*)in)[2 * i + 1];
    uint4 v;
    v.x = f2bf(a.x) | ((unsigned)f2bf(a.y) << 16);
    v.y = f2bf(a.z) | ((unsigned)f2bf(a.w) << 16);
    v.z = f2bf(b.x) | ((unsigned)f2bf(b.y) << 16);
    v.w = f2bf(b.z) | ((unsigned)f2bf(b.w) << 16);
    ((uint4*)out)[i] = v;
}

// C = A @ B^T in bf16 MFMA.  A: MxK bf16 row-major (ld=K), B: NxK bf16 row-major
// (ld=K), C: MxN fp32 (ld=ldc).  M % BM == 0, N % BN == 0, K % 32 == 0.
// 256 threads = 4 waves in 2x2; wave tile (BM/2)x(BN/2); 16x16x32 MFMA.
template<int BM, int BN>
__global__ __launch_bounds__(256)
void gemm_bf16(const unsigned short* __restrict__ A,
               const unsigned short* __restrict__ B,
               float* __restrict__ C, const int ldc, const int K)
{
    constexpr int FM = BM / 32;   // 16x16 fragments per wave along M
    constexpr int FN = BN / 32;
    __shared__ alignas(16) short As[BM * 32];
    __shared__ alignas(16) short Bs[BN * 32];

    const int tid  = threadIdx.x;
    const int wave = tid >> 6;
    const int lane = tid & 63;
    const long long row0 = (long long)blockIdx.y * BM;
    const long long col0 = (long long)blockIdx.x * BN;
    const int wm = (wave >> 1) * (BM / 2);
    const int wn = (wave & 1) * (BN / 2);

    f32x4 acc[FM][FN] = {};

    // staging map: thread t covers tile-row t/4, 16B chunk (t%4) within 64B row
    const int srow = tid >> 2;
    const int scol = (tid & 3) * 8;
    const unsigned short* gA = A + (row0 + srow) * K + scol;
    const unsigned short* gB = B + (col0 + srow) * K + scol;

    const int fr = lane & 15;          // fragment row/col within 16
    const int fk = (lane >> 4) * 8;    // k sub-block

    for (int kt = 0; kt < K; kt += 32) {
#pragma unroll
        for (int r = 0; r < BM; r += 64)
            gload_lds16(gA + (long long)r * K + kt, &As[r * 32 + tid * 8]);
#pragma unroll
        for (int r = 0; r < BN; r += 64)
            gload_lds16(gB + (long long)r * K + kt, &Bs[r * 32 + tid * 8]);
        __syncthreads();   // compiler drains vmcnt before s_barrier

        bf16x8 af[FM], bfr[FN];
#pragma unroll
        for (int mi = 0; mi < FM; ++mi)
            af[mi] = *(const bf16x8*)&As[(wm + mi * 16 + fr) * 32 + fk];
#pragma unroll
        for (int ni = 0; ni < FN; ++ni)
            bfr[ni] = *(const bf16x8*)&Bs[(wn + ni * 16 + fr) * 32 + fk];
#pragma unroll
        for (int mi = 0; mi < FM; ++mi)
#pragma unroll
            for (int ni = 0; ni < FN; ++ni)
                acc[mi][ni] = __builtin_amdgcn_mfma_f32_16x16x32_bf16(
                    af[mi], bfr[ni], acc[mi][ni], 0, 0, 0);
        __syncthreads();
    }

    const int cr = (lane >> 4) * 4;    // C/D: col=lane&15, row=(lane>>4)*4+reg
#pragma unroll
    for (int mi = 0; mi < FM; ++mi)
#pragma unroll
        for (int ni = 0; ni < FN; ++ni) {
            long long base = (row0 + wm + mi * 16 + cr) * ldc + col0 + wn + ni * 16 + fr;
#pragma unroll
            for (int r = 0; r < 4; ++r)
                C[base + (long long)r * ldc] = acc[mi][ni][r];
        }
}

// fp32 fallback GEMM: C = A @ B^T (used for the skinny mid-section matmuls)
template<int BM, int BN, int BK, int TM, int TN, int EPI>
__global__ __launch_bounds__(256)
void gemm_abT(const float* __restrict__ A, int lda,
              const float* __restrict__ B, int ldb,
              float* __restrict__ C, int ldc, long long zCstride,
              int M, int N, int K, int kspan,
              const float* __restrict__ bias)
{
    constexpr int PAD = 4;
    __shared__ float As[BK][BM + PAD];
    __shared__ float Bs[BK][BN + PAD];

    const int tid  = threadIdx.x;
    const int row0 = blockIdx.y * BM;
    const int col0 = blockIdx.x * BN;
    const int kstart = blockIdx.z * kspan;
    const int kend   = min(K, kstart + kspan);
    C += (long long)blockIdx.z * zCstride;

    constexpr int NX = BN / TN;
    const int tx = tid % NX;
    const int ty = tid / NX;

    float acc[TM][TN];
#pragma unroll
    for (int i = 0; i < TM; ++i)
#pragma unroll
        for (int j = 0; j < TN; ++j) acc[i][j] = 0.f;

    constexpr int KV = BK / 4;
    constexpr int ROWS_PER_PASS = 256 / KV;
    const int ak = (tid % KV) * 4;
    const int amBase = tid / KV;

    for (int kt = kstart; kt < kend; kt += BK) {
#pragma unroll
        for (int m = amBase; m < BM; m += ROWS_PER_PASS) {
            float4 v = *(const float4*)&A[(long long)(row0 + m) * lda + kt + ak];
            As[ak + 0][m] = v.x; As[ak + 1][m] = v.y;
            As[ak + 2][m] = v.z; As[ak + 3][m] = v.w;
        }
#pragma unroll
        for (int n = amBase; n < BN; n += ROWS_PER_PASS) {
            int gn = col0 + n;
            float4 v = make_float4(0.f, 0.f, 0.f, 0.f);
            if (gn < N) v = *(const float4*)&B[(long long)gn * ldb + kt + ak];
            Bs[ak + 0][n] = v.x; Bs[ak + 1][n] = v.y;
            Bs[ak + 2][n] = v.z; Bs[ak + 3][n] = v.w;
        }
        __syncthreads();
#pragma unroll
        for (int kk = 0; kk < BK; ++kk) {
            float a[TM], b[TN];
#pragma unroll
            for (int i = 0; i < TM; i += 4)
                *(float4*)&a[i] = *(const float4*)&As[kk][ty * TM + i];
#pragma unroll
            for (int j = 0; j < TN; j += 4)
                *(float4*)&b[j] = *(const float4*)&Bs[kk][tx * TN + j];
#pragma unroll
            for (int i = 0; i < TM; ++i)
#pragma unroll
                for (int j = 0; j < TN; ++j)
                    acc[i][j] = fmaf(a[i], b[j], acc[i][j]);
        }
        __syncthreads();
    }

#pragma unroll
    for (int i = 0; i < TM; ++i) {
        int row = row0 + ty * TM + i;
#pragma unroll
        for (int j = 0; j < TN; ++j) {
            int col = col0 + tx * TN + j;
            if (col < N) {
                float v = acc[i][j];
                if (EPI == 1) v = softplusf(v + bias[col]);
                C[(long long)row * ldc + col] = v;
            }
        }
    }
}

__global__ __launch_bounds__(256)
void conv_silu_kernel(const float* __restrict__ xz, const float* __restrict__ cw,
                      const float* __restrict__ cb, float* __restrict__ u)
{
    int i = blockIdx.x * 256 + threadIdx.x;
    int l = i >> 11;
    int d = i & (INNER - 1);
    float acc = cb[d];
#pragma unroll
    for (int j = 0; j < 4; ++j) {
        int ls = l - 3 + j;
        if (ls >= 0)
            acc = fmaf(cw[d * 4 + j], xz[(long long)ls * 4096 + d], acc);
    }
    u[i] = acc / (1.f + __expf(-acc));
}

__global__ __launch_bounds__(256)
void reduce_part(const float* __restrict__ part, float* __restrict__ projt)
{
    int i = blockIdx.x * 256 + threadIdx.x;
    float s = 0.f;
#pragma unroll
    for (int z = 0; z < 8; ++z) s += part[(long long)z * SEQLEN * NPROJ + i];
    projt[i] = s;
}

__global__ __launch_bounds__(256)
void scan_phase1(const float* __restrict__ delta, const float* __restrict__ u,
                 const float* __restrict__ projt, const float* __restrict__ A_log,
                 float* __restrict__ Sloc, float* __restrict__ sumd)
{
    __shared__ float BC[CHUNK][32];
    const int d  = blockIdx.x * 256 + threadIdx.x;
    const int c  = blockIdx.y;
    const int l0 = c * CHUNK;
    for (int i = threadIdx.x; i < CHUNK * 32; i += 256) {
        int l = i >> 5, j = i & 31;
        BC[l][j] = projt[(l0 + l) * NPROJ + DTRANK + j];
    }
    __syncthreads();

    float A2[DSTATE];
#pragma unroll
    for (int n = 0; n < DSTATE; ++n)
        A2[n] = -__expf(A_log[d * DSTATE + n]) * 1.4426950408889634f;

    float h[DSTATE];
#pragma unroll
    for (int n = 0; n < DSTATE; ++n) h[n] = 0.f;
    float sd = 0.f;

    for (int t = 0; t < CHUNK; ++t) {
        int l = l0 + t;
        float dl = delta[l * INNER + d];
        float ul = u[l * INNER + d];
        float du = dl * ul;
        sd += dl;
#pragma unroll
        for (int n = 0; n < DSTATE; ++n) {
            float dA = exp2f(dl * A2[n]);
            h[n] = fmaf(dA, h[n], du * BC[t][n]);
        }
    }
#pragma unroll
    for (int n = 0; n < DSTATE; ++n)
        Sloc[((long long)c * INNER + d) * DSTATE + n] = h[n];
    sumd[c * INNER + d] = sd;
}

// in-place: S[c] (chunk-local final states) -> H_init[c] (state at chunk start)
__global__ __launch_bounds__(256)
void scan_phase2(float* __restrict__ S, const float* __restrict__ sumd,
                 const float* __restrict__ A_log)
{
    int i = blockIdx.x * 256 + threadIdx.x;
    int d = i >> 4;
    float A2 = -__expf(A_log[i]) * 1.4426950408889634f;
    float H = 0.f;
#pragma unroll
    for (int c = 0; c < NCH; ++c) {
        float s = S[(long long)c * INNER * DSTATE + i];
        float P = exp2f(A2 * sumd[c * INNER + d]);
        S[(long long)c * INNER * DSTATE + i] = H;
        H = fmaf(P, H, s);
    }
}

// re-scan with correct init; y = (h.C + D*u) * silu(gate), emitted as bf16
__global__ __launch_bounds__(256)
void scan_phase3(const float* __restrict__ delta, const float* __restrict__ u,
                 const float* __restrict__ projt, const float* __restrict__ A_log,
                 const float* __restrict__ Hinit, const float* __restrict__ xz,
                 const float* __restrict__ D_skip, unsigned short* __restrict__ ybf)
{
    __shared__ float BC[CHUNK][32];
    const int d  = blockIdx.x * 256 + threadIdx.x;
    const int c  = blockIdx.y;
    const int l0 = c * CHUNK;
    for (int i = threadIdx.x; i < CHUNK * 32; i += 256) {
        int l = i >> 5, j = i & 31;
        BC[l][j] = projt[(l0 + l) * NPROJ + DTRANK + j];
    }
    __syncthreads();

    float A2[DSTATE];
#pragma unroll
    for (int n = 0; n < DSTATE; ++n)
        A2[n] = -__expf(A_log[d * DSTATE + n]) * 1.4426950408889634f;

    float h[DSTATE];
#pragma unroll
    for (int n = 0; n < DSTATE; ++n)
        h[n] = Hinit[((long long)c * INNER + d) * DSTATE + n];
    const float Dd = D_skip[d];

    for (int t = 0; t < CHUNK; ++t) {
        int l = l0 + t;
        float dl = delta[l * INNER + d];
        float ul = u[l * INNER + d];
        float du = dl * ul;
        float y = 0.f;
#pragma unroll
        for (int n = 0; n < DSTATE; ++n) {
            float dA = exp2f(dl * A2[n]);
            h[n] = fmaf(dA, h[n], du * BC[t][n]);
            y = fmaf(h[n], BC[t][16 + n], y);
        }
        float yv = fmaf(Dd, ul, y);
        float g = xz[(long long)l * 4096 + 2048 + d];
        float sg = g / (1.f + __expf(-g));
        ybf[(long long)l * INNER + d] = f2bf(yv * sg);
    }
}

extern "C" void kernel_launch(void* const* d_in, const int* in_sizes, int n_in,
                              void* d_out, int out_size, void* d_ws, size_t ws_size,
                              hipStream_t stream)
{
    const float* hidden  = (const float*)d_in[0];
    const float* W_in    = (const float*)d_in[1];
    const float* conv_w  = (const float*)d_in[2];
    const float* conv_b  = (const float*)d_in[3];
    const float* W_x     = (const float*)d_in[4];
    const float* W_dt    = (const float*)d_in[5];
    const float* dt_bias = (const float*)d_in[6];
    const float* A_log   = (const float*)d_in[7];
    const float* D_skip  = (const float*)d_in[8];
    const float* W_out   = (const float*)d_in[9];
    float* out = (float*)d_out;

    // workspace layout (80,740,352 B total), with lifetime-based aliasing:
    char* base = (char*)d_ws;
    float*          xz     = (float*)(base + 0);                  // [0, 33554432)
    float*          u      = (float*)(base + 33554432);           // [.., 50331648)
    unsigned short* Wout_b = (unsigned short*)(base + 33554432);  // aliases u (dead after phase3)
    float*          delta  = (float*)(base + 50331648);           // [.., 67108864)
    unsigned short* hid_b  = (unsigned short*)(base + 50331648);  // aliases delta (written later)
    unsigned short* Win_b  = (unsigned short*)(base + 54525952);  // aliases delta
    float*          projt  = (float*)(base + 67108864);           // [.., 67895296)
    float*          part   = (float*)(base + 67895296);           // [.., 76283904)
    unsigned short* y_b    = (unsigned short*)(base + 67895296);  // aliases part (dead after reduce)
    float*          Sloc   = (float*)(base + 76283904);           // [.., 80478208)  Hinit in-place
    float*          sumd   = (float*)(base + 80478208);           // [.., 80740352)

    // 0. fp32 -> bf16 operand conversions for GEMM1
    cvt_f32_bf16<<<1024, 256, 0, stream>>>(hidden, hid_b, 262144);
    cvt_f32_bf16<<<2048, 256, 0, stream>>>(W_in, Win_b, 524288);

    // 1. xz = hidden @ W_in^T   (2048 x 4096, K=1024), bf16 MFMA
    gemm_bf16<128, 128><<<dim3(32, 16, 1), 256, 0, stream>>>(hid_b, Win_b, xz, 4096, DMODEL);

    // 2. u = silu(causal depthwise conv(proj) + b)
    conv_silu_kernel<<<(SEQLEN * INNER) / 256, 256, 0, stream>>>(xz, conv_w, conv_b, u);

    // 3. projt = u @ W_x^T  (2048 x 96, K=2048) split-K 8-way + reduce (fp32)
    gemm_abT<128,128,16,8,8,0><<<dim3(1,16,8), 256, 0, stream>>>(
        u, INNER, W_x, INNER, part, NPROJ, (long long)SEQLEN * NPROJ,
        SEQLEN, NPROJ, INNER, INNER / 8, nullptr);
    reduce_part<<<(SEQLEN * NPROJ) / 256, 256, 0, stream>>>(part, projt);

    // 4. delta = softplus(dt_lr @ W_dt^T + dt_bias)  (2048 x 2048, K=64) fp32
    //    (clobbers hid_b/Win_b — dead after GEMM1)
    gemm_abT<128,128,16,8,8,1><<<dim3(16,16,1), 256, 0, stream>>>(
        projt, NPROJ, W_dt, DTRANK, delta, INNER, 0, SEQLEN, INNER, DTRANK, DTRANK, dt_bias);

    // 5-7. chunked selective scan + fused gated epilogue -> y (bf16)
    scan_phase1<<<dim3(INNER / 256, NCH), 256, 0, stream>>>(delta, u, projt, A_log, Sloc, sumd);
    scan_phase2<<<(INNER * DSTATE) / 256, 256, 0, stream>>>(Sloc, sumd, A_log);
    scan_phase3<<<dim3(INNER / 256, NCH), 256, 0, stream>>>(delta, u, projt, A_log,
                                                            Sloc, xz, D_skip, y_b);

    // 8. W_out -> bf16 (over u, dead now), then out = y @ W_out^T (2048x1024, K=2048)
    cvt_f32_bf16<<<1024, 256, 0, stream>>>(W_out, Wout_b, 262144);
    gemm_bf16<128, 64><<<dim3(16, 16, 1), 256, 0, stream>>>(y_b, Wout_b, out, DMODEL, INNER);
}

// Round 3
// 255.601 us; speedup vs baseline: 2.7572x; 1.2426x over previous
//
#include <hip/hip_runtime.h>
#include <hip/hip_bf16.h>

#define SEQLEN 2048
#define DMODEL 1024
#define INNER  2048
#define DSTATE 16
#define DTRANK 64
#define NPROJ  96   // DTRANK + 2*DSTATE
#define CHUNK  32
#define NCH    64   // SEQLEN / CHUNK

typedef __attribute__((ext_vector_type(8))) short bf16x8;
typedef __attribute__((ext_vector_type(4))) float f32x4;

__device__ __forceinline__ float softplusf(float x) {
    return (x > 20.f) ? x : log1pf(__expf(x));
}

// fp32 -> bf16 round-to-nearest-even (finite inputs)
__device__ __forceinline__ unsigned short f2bf(float x) {
    unsigned u = __float_as_uint(x);
    unsigned r = (u + 0x7FFF + ((u >> 16) & 1)) >> 16;
    return (unsigned short)r;
}
__device__ __forceinline__ float bf2f(unsigned short x) {
    return __uint_as_float((unsigned)x << 16);
}

__device__ __forceinline__ void gload_lds16(const void* g, void* l) {
    __builtin_amdgcn_global_load_lds(
        (__attribute__((address_space(1))) const unsigned int*)g,
        (__attribute__((address_space(3))) unsigned int*)l,
        16, 0, 0);
}

// two-segment fp32 -> bf16 conversion (8 elems per thread)
__global__ __launch_bounds__(256)
void cvt2_f32_bf16(const float* __restrict__ inA, unsigned short* __restrict__ outA, int n8A,
                   const float* __restrict__ inB, unsigned short* __restrict__ outB)
{
    int i = blockIdx.x * 256 + threadIdx.x;
    const float* in;
    unsigned short* out;
    if (i < n8A) { in = inA; out = outA; }
    else         { in = inB; out = outB; i -= n8A; }
    float4 a = ((const float4*)in)[2 * i];
    float4 b = ((const float4*)in)[2 * i + 1];
    uint4 v;
    v.x = f2bf(a.x) | ((unsigned)f2bf(a.y) << 16);
    v.y = f2bf(a.z) | ((unsigned)f2bf(a.w) << 16);
    v.z = f2bf(b.x) | ((unsigned)f2bf(b.y) << 16);
    v.w = f2bf(b.z) | ((unsigned)f2bf(b.w) << 16);
    ((uint4*)out)[i] = v;
}

__global__ __launch_bounds__(256)
void cvt_f32_bf16(const float* __restrict__ in, unsigned short* __restrict__ out, int n8)
{
    int i = blockIdx.x * 256 + threadIdx.x;
    if (i >= n8) return;
    float4 a = ((const float4*)in)[2 * i];
    float4 b = ((const float4*)in)[2 * i + 1];
    uint4 v;
    v.x = f2bf(a.x) | ((unsigned)f2bf(a.y) << 16);
    v.y = f2bf(a.z) | ((unsigned)f2bf(a.w) << 16);
    v.z = f2bf(b.x) | ((unsigned)f2bf(b.y) << 16);
    v.w = f2bf(b.z) | ((unsigned)f2bf(b.w) << 16);
    ((uint4*)out)[i] = v;
}

// C = A @ B^T in bf16 MFMA.  A: MxK bf16 (ld=K), B: NxK bf16 (ld=K), C: MxN fp32.
// 256 threads = 4 waves 2x2; wave tile (BM/2)x(BN/2); 16x16x32 MFMA.
template<int BM, int BN>
__global__ __launch_bounds__(256)
void gemm_bf16(const unsigned short* __restrict__ A,
               const unsigned short* __restrict__ B,
               float* __restrict__ C, const int ldc, const int K)
{
    constexpr int FM = BM / 32;
    constexpr int FN = BN / 32;
    __shared__ alignas(16) short As[BM * 32];
    __shared__ alignas(16) short Bs[BN * 32];

    const int tid  = threadIdx.x;
    const int wave = tid >> 6;
    const int lane = tid & 63;
    const long long row0 = (long long)blockIdx.y * BM;
    const long long col0 = (long long)blockIdx.x * BN;
    const int wm = (wave >> 1) * (BM / 2);
    const int wn = (wave & 1) * (BN / 2);

    f32x4 acc[FM][FN] = {};

    const int srow = tid >> 2;
    const int scol = (tid & 3) * 8;
    const unsigned short* gA = A + (row0 + srow) * K + scol;
    const unsigned short* gB = B + (col0 + srow) * K + scol;

    const int fr = lane & 15;
    const int fk = (lane >> 4) * 8;

    for (int kt = 0; kt < K; kt += 32) {
#pragma unroll
        for (int r = 0; r < BM; r += 64)
            gload_lds16(gA + (long long)r * K + kt, &As[r * 32 + tid * 8]);
#pragma unroll
        for (int r = 0; r < BN; r += 64)
            gload_lds16(gB + (long long)r * K + kt, &Bs[r * 32 + tid * 8]);
        __syncthreads();

        bf16x8 af[FM], bfr[FN];
#pragma unroll
        for (int mi = 0; mi < FM; ++mi)
            af[mi] = *(const bf16x8*)&As[(wm + mi * 16 + fr) * 32 + fk];
#pragma unroll
        for (int ni = 0; ni < FN; ++ni)
            bfr[ni] = *(const bf16x8*)&Bs[(wn + ni * 16 + fr) * 32 + fk];
#pragma unroll
        for (int mi = 0; mi < FM; ++mi)
#pragma unroll
            for (int ni = 0; ni < FN; ++ni)
                acc[mi][ni] = __builtin_amdgcn_mfma_f32_16x16x32_bf16(
                    af[mi], bfr[ni], acc[mi][ni], 0, 0, 0);
        __syncthreads();
    }

    const int cr = (lane >> 4) * 4;
#pragma unroll
    for (int mi = 0; mi < FM; ++mi)
#pragma unroll
        for (int ni = 0; ni < FN; ++ni) {
            long long base = (row0 + wm + mi * 16 + cr) * ldc + col0 + wn + ni * 16 + fr;
#pragma unroll
            for (int r = 0; r < 4; ++r)
                C[base + (long long)r * ldc] = acc[mi][ni][r];
        }
}

// fp32 GEMM: C = A @ B^T.  EPI=0 plain fp32 out; EPI=2 bf16 softplus(acc+bias) out.
template<int BM, int BN, int BK, int TM, int TN, int EPI>
__global__ __launch_bounds__(256)
void gemm_abT(const float* __restrict__ A, int lda,
              const float* __restrict__ B, int ldb,
              float* __restrict__ C, int ldc, long long zCstride,
              int M, int N, int K, int kspan,
              const float* __restrict__ bias)
{
    constexpr int PAD = 4;
    __shared__ float As[BK][BM + PAD];
    __shared__ float Bs[BK][BN + PAD];

    const int tid  = threadIdx.x;
    const int row0 = blockIdx.y * BM;
    const int col0 = blockIdx.x * BN;
    const int kstart = blockIdx.z * kspan;
    const int kend   = min(K, kstart + kspan);
    C += (long long)blockIdx.z * zCstride;

    constexpr int NX = BN / TN;
    const int tx = tid % NX;
    const int ty = tid / NX;

    float acc[TM][TN];
#pragma unroll
    for (int i = 0; i < TM; ++i)
#pragma unroll
        for (int j = 0; j < TN; ++j) acc[i][j] = 0.f;

    constexpr int KV = BK / 4;
    constexpr int ROWS_PER_PASS = 256 / KV;
    const int ak = (tid % KV) * 4;
    const int amBase = tid / KV;

    for (int kt = kstart; kt < kend; kt += BK) {
#pragma unroll
        for (int m = amBase; m < BM; m += ROWS_PER_PASS) {
            float4 v = *(const float4*)&A[(long long)(row0 + m) * lda + kt + ak];
            As[ak + 0][m] = v.x; As[ak + 1][m] = v.y;
            As[ak + 2][m] = v.z; As[ak + 3][m] = v.w;
        }
#pragma unroll
        for (int n = amBase; n < BN; n += ROWS_PER_PASS) {
            int gn = col0 + n;
            float4 v = make_float4(0.f, 0.f, 0.f, 0.f);
            if (gn < N) v = *(const float4*)&B[(long long)gn * ldb + kt + ak];
            Bs[ak + 0][n] = v.x; Bs[ak + 1][n] = v.y;
            Bs[ak + 2][n] = v.z; Bs[ak + 3][n] = v.w;
        }
        __syncthreads();
#pragma unroll
        for (int kk = 0; kk < BK; ++kk) {
            float a[TM], b[TN];
#pragma unroll
            for (int i = 0; i < TM; i += 4)
                *(float4*)&a[i] = *(const float4*)&As[kk][ty * TM + i];
#pragma unroll
            for (int j = 0; j < TN; j += 4)
                *(float4*)&b[j] = *(const float4*)&Bs[kk][tx * TN + j];
#pragma unroll
            for (int i = 0; i < TM; ++i)
#pragma unroll
                for (int j = 0; j < TN; ++j)
                    acc[i][j] = fmaf(a[i], b[j], acc[i][j]);
        }
        __syncthreads();
    }

#pragma unroll
    for (int i = 0; i < TM; ++i) {
        int row = row0 + ty * TM + i;
#pragma unroll
        for (int j = 0; j < TN; ++j) {
            int col = col0 + tx * TN + j;
            if (col < N) {
                float v = acc[i][j];
                if (EPI == 2) {
                    ((unsigned short*)C)[(long long)row * ldc + col] =
                        f2bf(softplusf(v + bias[col]));
                } else {
                    C[(long long)row * ldc + col] = v;
                }
            }
        }
    }
}

// u[l][d] = silu(conv(proj) + b), 4 channels per thread
__global__ __launch_bounds__(256)
void conv_silu_kernel(const float* __restrict__ xz, const float* __restrict__ cw,
                      const float* __restrict__ cb, float* __restrict__ u)
{
    int i = blockIdx.x * 256 + threadIdx.x;   // i < SEQLEN * 512
    int l  = i >> 9;
    int dq = i & 511;
    int d  = dq * 4;
    float4 wv[4];
#pragma unroll
    for (int k = 0; k < 4; ++k) wv[k] = ((const float4*)cw)[d + k];
    float4 acc = ((const float4*)cb)[dq];
#pragma unroll
    for (int j = 0; j < 4; ++j) {
        int ls = l - 3 + j;
        if (ls >= 0) {
            float4 x = *(const float4*)&xz[(long long)ls * 4096 + d];
            acc.x = fmaf(((const float*)&wv[0])[j], x.x, acc.x);
            acc.y = fmaf(((const float*)&wv[1])[j], x.y, acc.y);
            acc.z = fmaf(((const float*)&wv[2])[j], x.z, acc.z);
            acc.w = fmaf(((const float*)&wv[3])[j], x.w, acc.w);
        }
    }
    float4 r;
    r.x = acc.x / (1.f + __expf(-acc.x));
    r.y = acc.y / (1.f + __expf(-acc.y));
    r.z = acc.z / (1.f + __expf(-acc.z));
    r.w = acc.w / (1.f + __expf(-acc.w));
    ((float4*)u)[i] = r;
}

__global__ __launch_bounds__(256)
void reduce_part(const float* __restrict__ part, float* __restrict__ projt)
{
    int i = blockIdx.x * 256 + threadIdx.x;
    float s = 0.f;
#pragma unroll
    for (int z = 0; z < 8; ++z) s += part[(long long)z * SEQLEN * NPROJ + i];
    projt[i] = s;
}

// Phase 1: local chunk scans (h0=0) -> chunk-final states + per-chunk delta sums.
// Fully unrolled t-loop; delta/u loads hoisted to registers (latency hiding).
__global__ __launch_bounds__(256)
void scan_phase1(const unsigned short* __restrict__ delta_bf, const float* __restrict__ u,
                 const float* __restrict__ projt, const float* __restrict__ A_log,
                 float* __restrict__ Sloc, float* __restrict__ sumd)
{
    __shared__ float Bsh[CHUNK][16];
    const int d  = blockIdx.x * 256 + threadIdx.x;
    const int c  = blockIdx.y;
    const int l0 = c * CHUNK;
    for (int i = threadIdx.x; i < CHUNK * 16; i += 256) {
        int l = i >> 4, j = i & 15;
        Bsh[l][j] = projt[(l0 + l) * NPROJ + DTRANK + j];
    }
    __syncthreads();

    float A2[DSTATE];
#pragma unroll
    for (int n = 0; n < DSTATE; ++n)
        A2[n] = -__expf(A_log[d * DSTATE + n]) * 1.4426950408889634f;

    float dl[CHUNK], du[CHUNK];
#pragma unroll
    for (int t = 0; t < CHUNK; ++t) {
        int l = l0 + t;
        float dv = bf2f(delta_bf[l * INNER + d]);
        dl[t] = dv;
        du[t] = dv * u[l * INNER + d];
    }

    float h[DSTATE];
#pragma unroll
    for (int n = 0; n < DSTATE; ++n) h[n] = 0.f;
    float sd = 0.f;

#pragma unroll
    for (int t = 0; t < CHUNK; ++t) {
        sd += dl[t];
#pragma unroll
        for (int n = 0; n < DSTATE; ++n) {
            float dA = exp2f(dl[t] * A2[n]);
            h[n] = fmaf(dA, h[n], du[t] * Bsh[t][n]);
        }
    }
#pragma unroll
    for (int n = 0; n < DSTATE; ++n)
        Sloc[(c * INNER + d) * DSTATE + n] = h[n];
    sumd[c * INNER + d] = sd;
}

// Phase 2 (in-place): S[c] chunk-final -> state at chunk start. Fully unrolled.
__global__ __launch_bounds__(256)
void scan_phase2(float* __restrict__ S, const float* __restrict__ sumd,
                 const float* __restrict__ A_log)
{
    int i = blockIdx.x * 256 + threadIdx.x;   // i < INNER*DSTATE
    int d = i >> 4;
    float A2 = -__expf(A_log[i]) * 1.4426950408889634f;
    float H = 0.f;
#pragma unroll
    for (int c = 0; c < NCH; ++c) {
        float s = S[c * INNER * DSTATE + i];
        float P = exp2f(A2 * sumd[c * INNER + d]);
        S[c * INNER * DSTATE + i] = H;
        H = fmaf(P, H, s);
    }
}

// Phase 3: re-scan with correct init; y = (h.C + D*u) * silu(gate) -> bf16
__global__ __launch_bounds__(256)
void scan_phase3(const unsigned short* __restrict__ delta_bf, const float* __restrict__ u,
                 const float* __restrict__ projt, const float* __restrict__ A_log,
                 const float* __restrict__ Hinit, const float* __restrict__ xz,
                 const float* __restrict__ D_skip, unsigned short* __restrict__ ybf)
{
    __shared__ float BC[CHUNK][32];
    const int d  = blockIdx.x * 256 + threadIdx.x;
    const int c  = blockIdx.y;
    const int l0 = c * CHUNK;
    for (int i = threadIdx.x; i < CHUNK * 32; i += 256) {
        int l = i >> 5, j = i & 31;
        BC[l][j] = projt[(l0 + l) * NPROJ + DTRANK + j];
    }
    __syncthreads();

    float A2[DSTATE];
#pragma unroll
    for (int n = 0; n < DSTATE; ++n)
        A2[n] = -__expf(A_log[d * DSTATE + n]) * 1.4426950408889634f;

    float dl[CHUNK], uv[CHUNK];
#pragma unroll
    for (int t = 0; t < CHUNK; ++t) {
        int l = l0 + t;
        dl[t] = bf2f(delta_bf[l * INNER + d]);
        uv[t] = u[l * INNER + d];
    }

    float h[DSTATE];
#pragma unroll
    for (int n = 0; n < DSTATE; ++n)
        h[n] = Hinit[(c * INNER + d) * DSTATE + n];
    const float Dd = D_skip[d];

#pragma unroll
    for (int t = 0; t < CHUNK; ++t) {
        int l = l0 + t;
        float du = dl[t] * uv[t];
        float y = 0.f;
#pragma unroll
        for (int n = 0; n < DSTATE; ++n) {
            float dA = exp2f(dl[t] * A2[n]);
            h[n] = fmaf(dA, h[n], du * BC[t][n]);
            y = fmaf(h[n], BC[t][16 + n], y);
        }
        float yv = fmaf(Dd, uv[t], y);
        float g = xz[(long long)l * 4096 + 2048 + d];
        float sg = g / (1.f + __expf(-g));
        ybf[l * INNER + d] = f2bf(yv * sg);
    }
}

extern "C" void kernel_launch(void* const* d_in, const int* in_sizes, int n_in,
                              void* d_out, int out_size, void* d_ws, size_t ws_size,
                              hipStream_t stream)
{
    const float* hidden  = (const float*)d_in[0];
    const float* W_in    = (const float*)d_in[1];
    const float* conv_w  = (const float*)d_in[2];
    const float* conv_b  = (const float*)d_in[3];
    const float* W_x     = (const float*)d_in[4];
    const float* W_dt    = (const float*)d_in[5];
    const float* dt_bias = (const float*)d_in[6];
    const float* A_log   = (const float*)d_in[7];
    const float* D_skip  = (const float*)d_in[8];
    const float* W_out   = (const float*)d_in[9];
    float* out = (float*)d_out;

    // workspace layout, 76,808,192 B total (proven ceiling: 80.7MB in round 2)
    char* base = (char*)d_ws;
    float*          xz     = (float*)(base + 0);                  // 33.55MB, GEMM1->phase3(gate)
    float*          u      = (float*)(base + 33554432);           // 16.78MB, conv->phase3
    unsigned short* hid_b  = (unsigned short*)(base + 33554432);  // pre-GEMM1, aliases u
    unsigned short* Win_b  = (unsigned short*)(base + 37748736);  // pre-GEMM1, aliases u
    unsigned short* Wout_b = (unsigned short*)(base + 33554432);  // post-phase3, aliases u
    unsigned short* dlt_b  = (unsigned short*)(base + 50331648);  // 8.39MB bf16 delta
    float*          projt  = (float*)(base + 58720256);           // 0.79MB
    float*          part   = (float*)(base + 59506688);           // 6.29MB, xproj->reduce
    unsigned short* y_b    = (unsigned short*)(base + 59506688);  // 8.39MB, phase3->outGEMM (aliases part)
    float*          Sloc   = (float*)(base + 67895296);           // 8.39MB, phase1->phase3 (Hinit in-place)
    float*          sumd   = (float*)(base + 76283904);           // 0.52MB

    // 0. bf16 conversions for GEMM1 (one dispatch)
    cvt2_f32_bf16<<<3072, 256, 0, stream>>>(hidden, hid_b, 262144, W_in, Win_b);

    // 1. xz = hidden @ W_in^T  (2048 x 4096, K=1024) bf16 MFMA
    gemm_bf16<128, 128><<<dim3(32, 16, 1), 256, 0, stream>>>(hid_b, Win_b, xz, 4096, DMODEL);

    // 2. u = silu(causal depthwise conv(proj) + b)
    conv_silu_kernel<<<SEQLEN * 512 / 256, 256, 0, stream>>>(xz, conv_w, conv_b, u);

    // 3. projt = u @ W_x^T  (2048 x 96, K=2048) split-K 8-way fp32 + reduce
    gemm_abT<128,128,16,8,8,0><<<dim3(1,16,8), 256, 0, stream>>>(
        u, INNER, W_x, INNER, part, NPROJ, (long long)SEQLEN * NPROJ,
        SEQLEN, NPROJ, INNER, INNER / 8, nullptr);
    reduce_part<<<(SEQLEN * NPROJ) / 256, 256, 0, stream>>>(part, projt);

    // 4. delta = softplus(dt_lr @ W_dt^T + dt_bias) -> bf16  (2048 x 2048, K=64)
    gemm_abT<128,128,16,8,8,2><<<dim3(16,16,1), 256, 0, stream>>>(
        projt, NPROJ, W_dt, DTRANK, (float*)dlt_b, INNER, 0,
        SEQLEN, INNER, DTRANK, DTRANK, dt_bias);

    // 5-7. chunked selective scan (CHUNK=32, 512 blocks/phase) + fused epilogue
    scan_phase1<<<dim3(INNER / 256, NCH), 256, 0, stream>>>(dlt_b, u, projt, A_log, Sloc, sumd);
    scan_phase2<<<(INNER * DSTATE) / 256, 256, 0, stream>>>(Sloc, sumd, A_log);
    scan_phase3<<<dim3(INNER / 256, NCH), 256, 0, stream>>>(dlt_b, u, projt, A_log,
                                                            Sloc, xz, D_skip, y_b);

    // 8. W_out -> bf16 (over dead u), out = y @ W_out^T  (2048 x 1024, K=2048)
    cvt_f32_bf16<<<1024, 256, 0, stream>>>(W_out, Wout_b, 262144);
    gemm_bf16<128, 64><<<dim3(16, 16, 1), 256, 0, stream>>>(y_b, Wout_b, out, DMODEL, INNER);
}

// Round 4
// 192.685 us; speedup vs baseline: 3.6575x; 1.3265x over previous
//
#include <hip/hip_runtime.h>
#include <hip/hip_bf16.h>

#define SEQLEN 2048
#define DMODEL 1024
#define INNER  2048
#define DSTATE 16
#define DTRANK 64
#define NPROJ  96    // valid cols; padded to 128
#define NPAD   128
#define CHUNK  32
#define NCH    64    // SEQLEN / CHUNK

typedef __attribute__((ext_vector_type(8))) short bf16x8;
typedef __attribute__((ext_vector_type(4))) float f32x4;

__device__ __forceinline__ float softplusf(float x) {
    return (x > 20.f) ? x : log1pf(__expf(x));
}
__device__ __forceinline__ unsigned short f2bf(float x) {
    unsigned u = __float_as_uint(x);
    return (unsigned short)((u + 0x7FFF + ((u >> 16) & 1)) >> 16);
}
__device__ __forceinline__ float bf2f(unsigned short x) {
    return __uint_as_float((unsigned)x << 16);
}
__device__ __forceinline__ void gload_lds16(const void* g, void* l) {
    __builtin_amdgcn_global_load_lds(
        (__attribute__((address_space(1))) const unsigned int*)g,
        (__attribute__((address_space(3))) unsigned int*)l,
        16, 0, 0);
}
__device__ __forceinline__ void cvt8(const float* __restrict__ in,
                                     unsigned short* __restrict__ out, int i) {
    float4 a = ((const float4*)in)[2 * i];
    float4 b = ((const float4*)in)[2 * i + 1];
    uint4 v;
    v.x = f2bf(a.x) | ((unsigned)f2bf(a.y) << 16);
    v.y = f2bf(a.z) | ((unsigned)f2bf(a.w) << 16);
    v.z = f2bf(b.x) | ((unsigned)f2bf(b.y) << 16);
    v.w = f2bf(b.z) | ((unsigned)f2bf(b.w) << 16);
    ((uint4*)out)[i] = v;
}

// One-shot conversion of all bf16 operands.
// Segments (8-elem units): hidden 262144 | W_in 524288 | W_out 262144 |
// W_dt 16384 | W_x padded 96->128 rows 32768.  Total 1097728 units.
__global__ __launch_bounds__(256)
void cvt_all(const float* __restrict__ hidden, const float* __restrict__ W_in,
             const float* __restrict__ W_out, const float* __restrict__ W_dt,
             const float* __restrict__ W_x,
             unsigned short* __restrict__ hid_b, unsigned short* __restrict__ Win_b,
             unsigned short* __restrict__ Wout_b, unsigned short* __restrict__ Wdt_b,
             unsigned short* __restrict__ Wx_b)
{
    int i = blockIdx.x * 256 + threadIdx.x;
    if (i < 262144) { cvt8(hidden, hid_b, i); return; }
    i -= 262144;
    if (i < 524288) { cvt8(W_in, Win_b, i); return; }
    i -= 524288;
    if (i < 262144) { cvt8(W_out, Wout_b, i); return; }
    i -= 262144;
    if (i < 16384)  { cvt8(W_dt, Wdt_b, i); return; }
    i -= 16384;
    if (i < 32768) {
        int row = i >> 8;              // 256 units per 2048-wide row
        if (row < NPROJ) cvt8(W_x, Wx_b, i);
        else ((uint4*)Wx_b)[i] = make_uint4(0, 0, 0, 0);
    }
}

// C = A @ B^T, bf16 MFMA, fp32 accum.  A: MxK bf16 (ld=lda), B: NxK bf16
// (ld=ldb), C: MxN (ld=ldc, dtype per EPI).  256 thr = 4 waves 2x2;
// wave tile (BM/2)x(BN/2); 16x16x32 MFMA.  split-K via blockIdx.z.
// EPI 0: fp32 C.  EPI 2: bf16 C = f2bf(softplus(acc + bias[col])).
template<int BM, int BN, int EPI>
__global__ __launch_bounds__(256)
void gemm_bf16(const unsigned short* __restrict__ A, const int lda,
               const unsigned short* __restrict__ B, const int ldb,
               void* __restrict__ Cv, const int ldc, const long long zCstride,
               const int K, const int kspan, const float* __restrict__ bias)
{
    constexpr int FM = BM / 32;
    constexpr int FN = BN / 32;
    __shared__ alignas(16) short As[BM * 32];
    __shared__ alignas(16) short Bs[BN * 32];

    const int tid  = threadIdx.x;
    const int wave = tid >> 6;
    const int lane = tid & 63;
    const long long row0 = (long long)blockIdx.y * BM;
    const long long col0 = (long long)blockIdx.x * BN;
    const int wm = (wave >> 1) * (BM / 2);
    const int wn = (wave & 1) * (BN / 2);
    const int kstart = blockIdx.z * kspan;
    const int kend   = min(K, kstart + kspan);

    f32x4 acc[FM][FN] = {};

    const int srow = tid >> 2;
    const int scol = (tid & 3) * 8;
    const unsigned short* gA = A + (row0 + srow) * lda + scol;
    const unsigned short* gB = B + (col0 + srow) * ldb + scol;

    const int fr = lane & 15;
    const int fk = (lane >> 4) * 8;

    for (int kt = kstart; kt < kend; kt += 32) {
#pragma unroll
        for (int r = 0; r < BM; r += 64)
            gload_lds16(gA + (long long)r * lda + kt, &As[r * 32 + tid * 8]);
#pragma unroll
        for (int r = 0; r < BN; r += 64)
            gload_lds16(gB + (long long)r * ldb + kt, &Bs[r * 32 + tid * 8]);
        __syncthreads();

        bf16x8 af[FM], bfr[FN];
#pragma unroll
        for (int mi = 0; mi < FM; ++mi)
            af[mi] = *(const bf16x8*)&As[(wm + mi * 16 + fr) * 32 + fk];
#pragma unroll
        for (int ni = 0; ni < FN; ++ni)
            bfr[ni] = *(const bf16x8*)&Bs[(wn + ni * 16 + fr) * 32 + fk];
#pragma unroll
        for (int mi = 0; mi < FM; ++mi)
#pragma unroll
            for (int ni = 0; ni < FN; ++ni)
                acc[mi][ni] = __builtin_amdgcn_mfma_f32_16x16x32_bf16(
                    af[mi], bfr[ni], acc[mi][ni], 0, 0, 0);
        __syncthreads();
    }

    const int cr = (lane >> 4) * 4;    // C/D: col=lane&15, row=(lane>>4)*4+reg
#pragma unroll
    for (int mi = 0; mi < FM; ++mi)
#pragma unroll
        for (int ni = 0; ni < FN; ++ni) {
            long long rbase = row0 + wm + mi * 16 + cr;
            long long col   = col0 + wn + ni * 16 + fr;
#pragma unroll
            for (int r = 0; r < 4; ++r) {
                long long idx = (rbase + r) * ldc + col;
                if (EPI == 0) {
                    ((float*)Cv)[(long long)blockIdx.z * zCstride + idx] = acc[mi][ni][r];
                } else {
                    ((unsigned short*)Cv)[idx] = f2bf(softplusf(acc[mi][ni][r] + bias[col]));
                }
            }
        }
}

// u = silu(causal depthwise conv(proj) + b); emits fp32 u and bf16 u_b
__global__ __launch_bounds__(256)
void conv_silu_kernel(const float* __restrict__ xz, const float* __restrict__ cw,
                      const float* __restrict__ cb, float* __restrict__ u,
                      unsigned short* __restrict__ u_b)
{
    int i = blockIdx.x * 256 + threadIdx.x;   // i < SEQLEN * 512
    int l  = i >> 9;
    int dq = i & 511;
    int d  = dq * 4;
    float4 wv[4];
#pragma unroll
    for (int k = 0; k < 4; ++k) wv[k] = ((const float4*)cw)[d + k];
    float4 acc = ((const float4*)cb)[dq];
#pragma unroll
    for (int j = 0; j < 4; ++j) {
        int ls = l - 3 + j;
        if (ls >= 0) {
            float4 x = *(const float4*)&xz[(long long)ls * 4096 + d];
            acc.x = fmaf(((const float*)&wv[0])[j], x.x, acc.x);
            acc.y = fmaf(((const float*)&wv[1])[j], x.y, acc.y);
            acc.z = fmaf(((const float*)&wv[2])[j], x.z, acc.z);
            acc.w = fmaf(((const float*)&wv[3])[j], x.w, acc.w);
        }
    }
    float4 r;
    r.x = acc.x / (1.f + __expf(-acc.x));
    r.y = acc.y / (1.f + __expf(-acc.y));
    r.z = acc.z / (1.f + __expf(-acc.z));
    r.w = acc.w / (1.f + __expf(-acc.w));
    ((float4*)u)[i] = r;
    uint2 p;
    p.x = f2bf(r.x) | ((unsigned)f2bf(r.y) << 16);
    p.y = f2bf(r.z) | ((unsigned)f2bf(r.w) << 16);
    ((uint2*)u_b)[i] = p;
}

// projt[i] = sum_z part[z][i]; emits fp32 projt and bf16 projt_b (i < 2048*128)
__global__ __launch_bounds__(256)
void reduce_part(const float* __restrict__ part, float* __restrict__ projt,
                 unsigned short* __restrict__ projt_b)
{
    int i = blockIdx.x * 256 + threadIdx.x;
    float s = 0.f;
#pragma unroll
    for (int z = 0; z < 8; ++z) s += part[(long long)z * SEQLEN * NPAD + i];
    projt[i] = s;
    projt_b[i] = f2bf(s);
}

// Phase 1: local chunk scans (h0=0) -> chunk-final states + per-chunk delta sums
__global__ __launch_bounds__(256)
void scan_phase1(const unsigned short* __restrict__ delta_bf, const float* __restrict__ u,
                 const float* __restrict__ projt, const float* __restrict__ A_log,
                 float* __restrict__ Sloc, float* __restrict__ sumd)
{
    __shared__ float Bsh[CHUNK][16];
    const int d  = blockIdx.x * 256 + threadIdx.x;
    const int c  = blockIdx.y;
    const int l0 = c * CHUNK;
    for (int i = threadIdx.x; i < CHUNK * 16; i += 256) {
        int l = i >> 4, j = i & 15;
        Bsh[l][j] = projt[(l0 + l) * NPAD + DTRANK + j];
    }
    __syncthreads();

    float A2[DSTATE];
#pragma unroll
    for (int n = 0; n < DSTATE; ++n)
        A2[n] = -__expf(A_log[d * DSTATE + n]) * 1.4426950408889634f;

    float dl[CHUNK], du[CHUNK];
#pragma unroll
    for (int t = 0; t < CHUNK; ++t) {
        int l = l0 + t;
        float dv = bf2f(delta_bf[l * INNER + d]);
        dl[t] = dv;
        du[t] = dv * u[l * INNER + d];
    }

    float h[DSTATE];
#pragma unroll
    for (int n = 0; n < DSTATE; ++n) h[n] = 0.f;
    float sd = 0.f;

#pragma unroll
    for (int t = 0; t < CHUNK; ++t) {
        sd += dl[t];
#pragma unroll
        for (int n = 0; n < DSTATE; ++n) {
            float dA = exp2f(dl[t] * A2[n]);
            h[n] = fmaf(dA, h[n], du[t] * Bsh[t][n]);
        }
    }
#pragma unroll
    for (int n = 0; n < DSTATE; ++n)
        Sloc[(c * INNER + d) * DSTATE + n] = h[n];
    sumd[c * INNER + d] = sd;
}

// Phase 2 (in-place): S[c] chunk-final -> state at chunk start
__global__ __launch_bounds__(256)
void scan_phase2(float* __restrict__ S, const float* __restrict__ sumd,
                 const float* __restrict__ A_log)
{
    int i = blockIdx.x * 256 + threadIdx.x;   // i < INNER*DSTATE
    int d = i >> 4;
    float A2 = -__expf(A_log[i]) * 1.4426950408889634f;
    float H = 0.f;
#pragma unroll
    for (int c = 0; c < NCH; ++c) {
        float s = S[c * INNER * DSTATE + i];
        float P = exp2f(A2 * sumd[c * INNER + d]);
        S[c * INNER * DSTATE + i] = H;
        H = fmaf(P, H, s);
    }
}

// Phase 3: re-scan; y = (h.C + D*u) * silu(gate) -> bf16 into proj half of xz
__global__ __launch_bounds__(256)
void scan_phase3(const unsigned short* __restrict__ delta_bf, const float* __restrict__ u,
                 const float* __restrict__ projt, const float* __restrict__ A_log,
                 const float* __restrict__ Hinit, const float* __restrict__ xz,
                 const float* __restrict__ D_skip, unsigned short* __restrict__ ybf)
{
    __shared__ float BC[CHUNK][32];
    const int d  = blockIdx.x * 256 + threadIdx.x;
    const int c  = blockIdx.y;
    const int l0 = c * CHUNK;
    for (int i = threadIdx.x; i < CHUNK * 32; i += 256) {
        int l = i >> 5, j = i & 31;
        BC[l][j] = projt[(l0 + l) * NPAD + DTRANK + j];
    }
    __syncthreads();

    float A2[DSTATE];
#pragma unroll
    for (int n = 0; n < DSTATE; ++n)
        A2[n] = -__expf(A_log[d * DSTATE + n]) * 1.4426950408889634f;

    float dl[CHUNK], uv[CHUNK];
#pragma unroll
    for (int t = 0; t < CHUNK; ++t) {
        int l = l0 + t;
        dl[t] = bf2f(delta_bf[l * INNER + d]);
        uv[t] = u[l * INNER + d];
    }

    float h[DSTATE];
#pragma unroll
    for (int n = 0; n < DSTATE; ++n)
        h[n] = Hinit[(c * INNER + d) * DSTATE + n];
    const float Dd = D_skip[d];

#pragma unroll
    for (int t = 0; t < CHUNK; ++t) {
        int l = l0 + t;
        float du = dl[t] * uv[t];
        float y = 0.f;
#pragma unroll
        for (int n = 0; n < DSTATE; ++n) {
            float dA = exp2f(dl[t] * A2[n]);
            h[n] = fmaf(dA, h[n], du * BC[t][n]);
            y = fmaf(h[n], BC[t][16 + n], y);
        }
        float yv = fmaf(Dd, uv[t], y);
        float g = xz[(long long)l * 4096 + 2048 + d];
        float sg = g / (1.f + __expf(-g));
        ybf[l * 8192 + d] = f2bf(yv * sg);   // proj half of xz, bf16, row stride 8192
    }
}

extern "C" void kernel_launch(void* const* d_in, const int* in_sizes, int n_in,
                              void* d_out, int out_size, void* d_ws, size_t ws_size,
                              hipStream_t stream)
{
    const float* hidden  = (const float*)d_in[0];
    const float* W_in    = (const float*)d_in[1];
    const float* conv_w  = (const float*)d_in[2];
    const float* conv_b  = (const float*)d_in[3];
    const float* W_x     = (const float*)d_in[4];
    const float* W_dt    = (const float*)d_in[5];
    const float* dt_bias = (const float*)d_in[6];
    const float* A_log   = (const float*)d_in[7];
    const float* D_skip  = (const float*)d_in[8];
    const float* W_out   = (const float*)d_in[9];
    float* out = (float*)d_out;

    // workspace layout, 82,575,360 B total (proven ceiling 84.9 MB, round 1)
    char* base = (char*)d_ws;
    float*          xz      = (float*)(base + 0);                 // 33.55MB; proj half becomes y_b
    unsigned short* y_b     = (unsigned short*)(base + 0);        // bf16 y, lda=8192 (in xz proj half)
    float*          u       = (float*)(base + 33554432);          // 16.78MB
    unsigned short* hid_b   = (unsigned short*)(base + 33554432); // pre-GEMM1 alias of u
    unsigned short* Win_b   = (unsigned short*)(base + 37748736); // pre-GEMM1 alias of u
    unsigned short* dlt_b   = (unsigned short*)(base + 50331648); // 8.39MB
    unsigned short* u_b     = (unsigned short*)(base + 58720256); // 8.39MB
    float*          part    = (float*)(base + 67108864);          // 8.39MB; Sloc aliases after reduce
    float*          Sloc    = (float*)(base + 67108864);
    float*          projt   = (float*)(base + 75497472);          // 1.05MB (2048 x 128 padded)
    unsigned short* projt_b = (unsigned short*)(base + 76546048); // 0.52MB
    unsigned short* Wout_b  = (unsigned short*)(base + 77070336); // 4.19MB
    unsigned short* Wx_b    = (unsigned short*)(base + 81264640); // 0.52MB (128 x 2048 padded)
    unsigned short* Wdt_b   = (unsigned short*)(base + 81788928); // 0.26MB
    float*          sumd    = (float*)(base + 82051072);          // 0.52MB

    // 0. all bf16 conversions in one dispatch (1097728 8-elem units)
    cvt_all<<<4289, 256, 0, stream>>>(hidden, W_in, W_out, W_dt, W_x,
                                      hid_b, Win_b, Wout_b, Wdt_b, Wx_b);

    // 1. xz = hidden @ W_in^T  (2048 x 4096, K=1024) bf16 MFMA
    gemm_bf16<128, 128, 0><<<dim3(32, 16, 1), 256, 0, stream>>>(
        hid_b, DMODEL, Win_b, DMODEL, xz, 4096, 0, DMODEL, DMODEL, nullptr);

    // 2. u = silu(conv(proj) + b)  (also emits bf16 u_b)
    conv_silu_kernel<<<SEQLEN * 512 / 256, 256, 0, stream>>>(xz, conv_w, conv_b, u, u_b);

    // 3. projt = u @ W_x^T  (2048 x 128pad, K=2048) bf16 MFMA split-K 8 + reduce
    gemm_bf16<128, 128, 0><<<dim3(1, 16, 8), 256, 0, stream>>>(
        u_b, INNER, Wx_b, INNER, part, NPAD, (long long)SEQLEN * NPAD,
        INNER, INNER / 8, nullptr);
    reduce_part<<<SEQLEN * NPAD / 256, 256, 0, stream>>>(part, projt, projt_b);

    // 4. delta = softplus(dt_lr @ W_dt^T + dt_bias) -> bf16  (2048 x 2048, K=64)
    gemm_bf16<128, 128, 2><<<dim3(16, 16, 1), 256, 0, stream>>>(
        projt_b, NPAD, Wdt_b, DTRANK, dlt_b, INNER, 0, DTRANK, DTRANK, dt_bias);

    // 5-7. chunked selective scan (CHUNK=32) + fused gated epilogue -> y_b in xz
    scan_phase1<<<dim3(INNER / 256, NCH), 256, 0, stream>>>(dlt_b, u, projt, A_log, Sloc, sumd);
    scan_phase2<<<(INNER * DSTATE) / 256, 256, 0, stream>>>(Sloc, sumd, A_log);
    scan_phase3<<<dim3(INNER / 256, NCH), 256, 0, stream>>>(dlt_b, u, projt, A_log,
                                                            Sloc, xz, D_skip, y_b);

    // 8. out = y @ W_out^T  (2048 x 1024, K=2048) bf16 MFMA
    gemm_bf16<128, 64, 0><<<dim3(16, 16, 1), 256, 0, stream>>>(
        y_b, 8192, Wout_b, INNER, out, DMODEL, 0, INNER, INNER, nullptr);
}

// Round 5
// 191.532 us; speedup vs baseline: 3.6795x; 1.0060x over previous
//
#include <hip/hip_runtime.h>
#include <hip/hip_bf16.h>

#define SEQLEN 2048
#define DMODEL 1024
#define INNER  2048
#define DSTATE 16
#define DTRANK 64
#define NPROJ  96    // valid rows of W_x; padded to 128
#define NPAD   128
#define CHUNK  32
#define NCH    64    // SEQLEN / CHUNK

typedef __attribute__((ext_vector_type(8))) short bf16x8;
typedef __attribute__((ext_vector_type(4))) float f32x4;

__device__ __forceinline__ float softplusf(float x) {
    return (x > 20.f) ? x : log1pf(__expf(x));
}
__device__ __forceinline__ unsigned short f2bf(float x) {
    unsigned u = __float_as_uint(x);
    return (unsigned short)((u + 0x7FFF + ((u >> 16) & 1)) >> 16);
}
__device__ __forceinline__ float bf2f(unsigned short x) {
    return __uint_as_float((unsigned)x << 16);
}
__device__ __forceinline__ void gload_lds16(const void* g, void* l) {
    __builtin_amdgcn_global_load_lds(
        (__attribute__((address_space(1))) const unsigned int*)g,
        (__attribute__((address_space(3))) unsigned int*)l,
        16, 0, 0);
}
__device__ __forceinline__ void cvt8(const float* __restrict__ in,
                                     unsigned short* __restrict__ out, int i) {
    float4 a = ((const float4*)in)[2 * i];
    float4 b = ((const float4*)in)[2 * i + 1];
    uint4 v;
    v.x = f2bf(a.x) | ((unsigned)f2bf(a.y) << 16);
    v.y = f2bf(a.z) | ((unsigned)f2bf(a.w) << 16);
    v.z = f2bf(b.x) | ((unsigned)f2bf(b.y) << 16);
    v.w = f2bf(b.z) | ((unsigned)f2bf(b.w) << 16);
    ((uint4*)out)[i] = v;
}

// One-shot conversion of all bf16 operands.
// Segments (8-elem units): hidden 262144 | W_in 524288 | W_out 262144 |
// W_dt 16384 | W_x padded 96->128 rows 32768.  Total 1097728 units.
__global__ __launch_bounds__(256)
void cvt_all(const float* __restrict__ hidden, const float* __restrict__ W_in,
             const float* __restrict__ W_out, const float* __restrict__ W_dt,
             const float* __restrict__ W_x,
             unsigned short* __restrict__ hid_b, unsigned short* __restrict__ Win_b,
             unsigned short* __restrict__ Wout_b, unsigned short* __restrict__ Wdt_b,
             unsigned short* __restrict__ Wx_b)
{
    int i = blockIdx.x * 256 + threadIdx.x;
    if (i < 262144) { cvt8(hidden, hid_b, i); return; }
    i -= 262144;
    if (i < 524288) { cvt8(W_in, Win_b, i); return; }
    i -= 524288;
    if (i < 262144) { cvt8(W_out, Wout_b, i); return; }
    i -= 262144;
    if (i < 16384)  { cvt8(W_dt, Wdt_b, i); return; }
    i -= 16384;
    if (i < 32768) {
        int row = i >> 8;              // 256 units per 2048-wide row
        if (row < NPROJ) cvt8(W_x, Wx_b, i);
        else ((uint4*)Wx_b)[i] = make_uint4(0, 0, 0, 0);
    }
}

// C = A @ B^T, bf16 MFMA, fp32 accum.  A: MxK bf16 (ld=lda), B: NxK bf16
// (ld=ldb).  256 thr = 4 waves 2x2; wave tile (BM/2)x(BN/2); 16x16x32 MFMA.
// split-K via blockIdx.z (EPI 0 only).
// EPI 0: fp32 C.  EPI 1: bf16 C.  EPI 2: bf16 C = softplus(acc + bias[col]).
template<int BM, int BN, int EPI>
__global__ __launch_bounds__(256)
void gemm_bf16(const unsigned short* __restrict__ A, const int lda,
               const unsigned short* __restrict__ B, const int ldb,
               void* __restrict__ Cv, const int ldc, const long long zCstride,
               const int K, const int kspan, const float* __restrict__ bias)
{
    constexpr int FM = BM / 32;
    constexpr int FN = BN / 32;
    __shared__ alignas(16) short As[BM * 32];
    __shared__ alignas(16) short Bs[BN * 32];

    const int tid  = threadIdx.x;
    const int wave = tid >> 6;
    const int lane = tid & 63;
    const long long row0 = (long long)blockIdx.y * BM;
    const long long col0 = (long long)blockIdx.x * BN;
    const int wm = (wave >> 1) * (BM / 2);
    const int wn = (wave & 1) * (BN / 2);
    const int kstart = blockIdx.z * kspan;
    const int kend   = min(K, kstart + kspan);

    f32x4 acc[FM][FN] = {};

    const int srow = tid >> 2;
    const int scol = (tid & 3) * 8;
    const unsigned short* gA = A + (row0 + srow) * lda + scol;
    const unsigned short* gB = B + (col0 + srow) * ldb + scol;

    const int fr = lane & 15;
    const int fk = (lane >> 4) * 8;

    for (int kt = kstart; kt < kend; kt += 32) {
#pragma unroll
        for (int r = 0; r < BM; r += 64)
            gload_lds16(gA + (long long)r * lda + kt, &As[r * 32 + tid * 8]);
#pragma unroll
        for (int r = 0; r < BN; r += 64)
            gload_lds16(gB + (long long)r * ldb + kt, &Bs[r * 32 + tid * 8]);
        __syncthreads();

        bf16x8 af[FM], bfr[FN];
#pragma unroll
        for (int mi = 0; mi < FM; ++mi)
            af[mi] = *(const bf16x8*)&As[(wm + mi * 16 + fr) * 32 + fk];
#pragma unroll
        for (int ni = 0; ni < FN; ++ni)
            bfr[ni] = *(const bf16x8*)&Bs[(wn + ni * 16 + fr) * 32 + fk];
#pragma unroll
        for (int mi = 0; mi < FM; ++mi)
#pragma unroll
            for (int ni = 0; ni < FN; ++ni)
                acc[mi][ni] = __builtin_amdgcn_mfma_f32_16x16x32_bf16(
                    af[mi], bfr[ni], acc[mi][ni], 0, 0, 0);
        __syncthreads();
    }

    const int cr = (lane >> 4) * 4;    // C/D: col=lane&15, row=(lane>>4)*4+reg
#pragma unroll
    for (int mi = 0; mi < FM; ++mi)
#pragma unroll
        for (int ni = 0; ni < FN; ++ni) {
            long long rbase = row0 + wm + mi * 16 + cr;
            long long col   = col0 + wn + ni * 16 + fr;
#pragma unroll
            for (int r = 0; r < 4; ++r) {
                long long idx = (rbase + r) * ldc + col;
                if (EPI == 0) {
                    ((float*)Cv)[(long long)blockIdx.z * zCstride + idx] = acc[mi][ni][r];
                } else if (EPI == 1) {
                    ((unsigned short*)Cv)[idx] = f2bf(acc[mi][ni][r]);
                } else {
                    ((unsigned short*)Cv)[idx] = f2bf(softplusf(acc[mi][ni][r] + bias[col]));
                }
            }
        }
}

// u = silu(causal depthwise conv(proj_bf16) + b) -> bf16 u_b, 4 channels/thread
__global__ __launch_bounds__(256)
void conv_silu_kernel(const unsigned short* __restrict__ xz_b, const float* __restrict__ cw,
                      const float* __restrict__ cb, unsigned short* __restrict__ u_b)
{
    int i = blockIdx.x * 256 + threadIdx.x;   // i < SEQLEN * 512
    int l  = i >> 9;
    int dq = i & 511;
    int d  = dq * 4;
    float4 wv[4];
#pragma unroll
    for (int k = 0; k < 4; ++k) wv[k] = ((const float4*)cw)[d + k];
    float4 acc = ((const float4*)cb)[dq];
#pragma unroll
    for (int j = 0; j < 4; ++j) {
        int ls = l - 3 + j;
        if (ls >= 0) {
            ushort4 x = *(const ushort4*)&xz_b[(long long)ls * 4096 + d];
            acc.x = fmaf(((const float*)&wv[0])[j], bf2f(x.x), acc.x);
            acc.y = fmaf(((const float*)&wv[1])[j], bf2f(x.y), acc.y);
            acc.z = fmaf(((const float*)&wv[2])[j], bf2f(x.z), acc.z);
            acc.w = fmaf(((const float*)&wv[3])[j], bf2f(x.w), acc.w);
        }
    }
    float4 r;
    r.x = acc.x / (1.f + __expf(-acc.x));
    r.y = acc.y / (1.f + __expf(-acc.y));
    r.z = acc.z / (1.f + __expf(-acc.z));
    r.w = acc.w / (1.f + __expf(-acc.w));
    uint2 p;
    p.x = f2bf(r.x) | ((unsigned)f2bf(r.y) << 16);
    p.y = f2bf(r.z) | ((unsigned)f2bf(r.w) << 16);
    ((uint2*)u_b)[i] = p;
}

// projt[i] = sum_z part[z][i]; emits fp32 projt and bf16 projt_b (i < 2048*128)
__global__ __launch_bounds__(256)
void reduce_part(const float* __restrict__ part, float* __restrict__ projt,
                 unsigned short* __restrict__ projt_b)
{
    int i = blockIdx.x * 256 + threadIdx.x;
    float s = 0.f;
#pragma unroll
    for (int z = 0; z < 8; ++z) s += part[(long long)z * SEQLEN * NPAD + i];
    projt[i] = s;
    projt_b[i] = f2bf(s);
}

// Phase 1: local chunk scans (h0=0) -> chunk-final states + per-chunk delta sums
__global__ __launch_bounds__(256)
void scan_phase1(const unsigned short* __restrict__ delta_bf,
                 const unsigned short* __restrict__ u_b,
                 const float* __restrict__ projt, const float* __restrict__ A_log,
                 float* __restrict__ Sloc, float* __restrict__ sumd)
{
    __shared__ float Bsh[CHUNK][16];
    const int d  = blockIdx.x * 256 + threadIdx.x;
    const int c  = blockIdx.y;
    const int l0 = c * CHUNK;
    for (int i = threadIdx.x; i < CHUNK * 16; i += 256) {
        int l = i >> 4, j = i & 15;
        Bsh[l][j] = projt[(l0 + l) * NPAD + DTRANK + j];
    }
    __syncthreads();

    float A2[DSTATE];
#pragma unroll
    for (int n = 0; n < DSTATE; ++n)
        A2[n] = -__expf(A_log[d * DSTATE + n]) * 1.4426950408889634f;

    float dl[CHUNK], du[CHUNK];
#pragma unroll
    for (int t = 0; t < CHUNK; ++t) {
        int l = l0 + t;
        float dv = bf2f(delta_bf[l * INNER + d]);
        dl[t] = dv;
        du[t] = dv * bf2f(u_b[l * INNER + d]);
    }

    float h[DSTATE];
#pragma unroll
    for (int n = 0; n < DSTATE; ++n) h[n] = 0.f;
    float sd = 0.f;

#pragma unroll
    for (int t = 0; t < CHUNK; ++t) {
        sd += dl[t];
#pragma unroll
        for (int n = 0; n < DSTATE; ++n) {
            float dA = exp2f(dl[t] * A2[n]);
            h[n] = fmaf(dA, h[n], du[t] * Bsh[t][n]);
        }
    }
#pragma unroll
    for (int n = 0; n < DSTATE; ++n)
        Sloc[(c * INNER + d) * DSTATE + n] = h[n];
    sumd[c * INNER + d] = sd;
}

// Phase 2 (in-place): S[c] chunk-final -> state at chunk start
__global__ __launch_bounds__(256)
void scan_phase2(float* __restrict__ S, const float* __restrict__ sumd,
                 const float* __restrict__ A_log)
{
    int i = blockIdx.x * 256 + threadIdx.x;   // i < INNER*DSTATE
    int d = i >> 4;
    float A2 = -__expf(A_log[i]) * 1.4426950408889634f;
    float H = 0.f;
#pragma unroll
    for (int c = 0; c < NCH; ++c) {
        float s = S[c * INNER * DSTATE + i];
        float P = exp2f(A2 * sumd[c * INNER + d]);
        S[c * INNER * DSTATE + i] = H;
        H = fmaf(P, H, s);
    }
}

// Phase 3: re-scan; y = (h.C + D*u) * silu(gate_bf16) -> bf16 y_b (ld=2048)
__global__ __launch_bounds__(256)
void scan_phase3(const unsigned short* __restrict__ delta_bf,
                 const unsigned short* __restrict__ u_b,
                 const float* __restrict__ projt, const float* __restrict__ A_log,
                 const float* __restrict__ Hinit, const unsigned short* __restrict__ xz_b,
                 const float* __restrict__ D_skip, unsigned short* __restrict__ ybf)
{
    __shared__ float BC[CHUNK][32];
    const int d  = blockIdx.x * 256 + threadIdx.x;
    const int c  = blockIdx.y;
    const int l0 = c * CHUNK;
    for (int i = threadIdx.x; i < CHUNK * 32; i += 256) {
        int l = i >> 5, j = i & 31;
        BC[l][j] = projt[(l0 + l) * NPAD + DTRANK + j];
    }
    __syncthreads();

    float A2[DSTATE];
#pragma unroll
    for (int n = 0; n < DSTATE; ++n)
        A2[n] = -__expf(A_log[d * DSTATE + n]) * 1.4426950408889634f;

    float dl[CHUNK], uv[CHUNK];
#pragma unroll
    for (int t = 0; t < CHUNK; ++t) {
        int l = l0 + t;
        dl[t] = bf2f(delta_bf[l * INNER + d]);
        uv[t] = bf2f(u_b[l * INNER + d]);
    }

    float h[DSTATE];
#pragma unroll
    for (int n = 0; n < DSTATE; ++n)
        h[n] = Hinit[(c * INNER + d) * DSTATE + n];
    const float Dd = D_skip[d];

#pragma unroll
    for (int t = 0; t < CHUNK; ++t) {
        int l = l0 + t;
        float du = dl[t] * uv[t];
        float y = 0.f;
#pragma unroll
        for (int n = 0; n < DSTATE; ++n) {
            float dA = exp2f(dl[t] * A2[n]);
            h[n] = fmaf(dA, h[n], du * BC[t][n]);
            y = fmaf(h[n], BC[t][16 + n], y);
        }
        float yv = fmaf(Dd, uv[t], y);
        float g = bf2f(xz_b[(long long)l * 4096 + 2048 + d]);
        float sg = g / (1.f + __expf(-g));
        ybf[l * INNER + d] = f2bf(yv * sg);
    }
}

extern "C" void kernel_launch(void* const* d_in, const int* in_sizes, int n_in,
                              void* d_out, int out_size, void* d_ws, size_t ws_size,
                              hipStream_t stream)
{
    const float* hidden  = (const float*)d_in[0];
    const float* W_in    = (const float*)d_in[1];
    const float* conv_w  = (const float*)d_in[2];
    const float* conv_b  = (const float*)d_in[3];
    const float* W_x     = (const float*)d_in[4];
    const float* W_dt    = (const float*)d_in[5];
    const float* dt_bias = (const float*)d_in[6];
    const float* A_log   = (const float*)d_in[7];
    const float* D_skip  = (const float*)d_in[8];
    const float* W_out   = (const float*)d_in[9];
    float* out = (float*)d_out;

    // workspace layout, ~61.6 MB total (proven ceiling 82.8 MB)
    char* base = (char*)d_ws;
    unsigned short* xz_b    = (unsigned short*)(base + 0);         // 16.78MB bf16 proj|gate
    unsigned short* hid_b   = (unsigned short*)(base + 16777216);  // 4.19MB (dead after GEMM1)
    unsigned short* Win_b   = (unsigned short*)(base + 20971520);  // 16.78MB (dead after GEMM1)
    unsigned short* u_b     = (unsigned short*)(base + 16777216);  // 8.39MB, aliases hid_b/Win_b head
    float*          part    = (float*)(base + 25165824);           // 8.39MB, aliases Win_b tail
    float*          Sloc    = (float*)(base + 25165824);           // aliases part after reduce
    unsigned short* dlt_b   = (unsigned short*)(base + 37748736);  // 8.39MB
    unsigned short* y_b     = (unsigned short*)(base + 46137344);  // 8.39MB
    float*          projt   = (float*)(base + 54525952);           // 1.05MB (2048 x 128)
    unsigned short* projt_b = (unsigned short*)(base + 55574528);  // 0.52MB
    unsigned short* Wout_b  = (unsigned short*)(base + 56098816);  // 4.19MB
    unsigned short* Wx_b    = (unsigned short*)(base + 60293120);  // 0.52MB (128 x 2048)
    unsigned short* Wdt_b   = (unsigned short*)(base + 60817408);  // 0.26MB
    float*          sumd    = (float*)(base + 61079552);           // 0.52MB

    // 0. all bf16 conversions in one dispatch (1097728 8-elem units)
    cvt_all<<<4289, 256, 0, stream>>>(hidden, W_in, W_out, W_dt, W_x,
                                      hid_b, Win_b, Wout_b, Wdt_b, Wx_b);

    // 1. xz = hidden @ W_in^T  (2048 x 4096, K=1024) bf16 MFMA -> bf16 out
    gemm_bf16<128, 128, 1><<<dim3(32, 16, 1), 256, 0, stream>>>(
        hid_b, DMODEL, Win_b, DMODEL, xz_b, 4096, 0, DMODEL, DMODEL, nullptr);

    // 2. u_b = silu(conv(proj_bf16) + b)  (bf16 only)
    conv_silu_kernel<<<SEQLEN * 512 / 256, 256, 0, stream>>>(xz_b, conv_w, conv_b, u_b);

    // 3. projt = u @ W_x^T  (2048 x 128pad, K=2048) bf16 MFMA split-K 8 + reduce
    gemm_bf16<128, 128, 0><<<dim3(1, 16, 8), 256, 0, stream>>>(
        u_b, INNER, Wx_b, INNER, part, NPAD, (long long)SEQLEN * NPAD,
        INNER, INNER / 8, nullptr);
    reduce_part<<<SEQLEN * NPAD / 256, 256, 0, stream>>>(part, projt, projt_b);

    // 4. delta = softplus(dt_lr @ W_dt^T + dt_bias) -> bf16  (2048 x 2048, K=64)
    gemm_bf16<128, 128, 2><<<dim3(16, 16, 1), 256, 0, stream>>>(
        projt_b, NPAD, Wdt_b, DTRANK, dlt_b, INNER, 0, DTRANK, DTRANK, dt_bias);

    // 5-7. chunked selective scan (CHUNK=32) + fused gated epilogue -> y_b
    scan_phase1<<<dim3(INNER / 256, NCH), 256, 0, stream>>>(dlt_b, u_b, projt, A_log, Sloc, sumd);
    scan_phase2<<<(INNER * DSTATE) / 256, 256, 0, stream>>>(Sloc, sumd, A_log);
    scan_phase3<<<dim3(INNER / 256, NCH), 256, 0, stream>>>(dlt_b, u_b, projt, A_log,
                                                            Sloc, xz_b, D_skip, y_b);

    // 8. out = y @ W_out^T  (2048 x 1024, K=2048) bf16 MFMA -> fp32 out
    gemm_bf16<128, 64, 0><<<dim3(16, 16, 1), 256, 0, stream>>>(
        y_b, INNER, Wout_b, INNER, out, DMODEL, 0, INNER, INNER, nullptr);
}

// Round 6
// 172.994 us; speedup vs baseline: 4.0737x; 1.1072x over previous
//
#include <hip/hip_runtime.h>
#include <hip/hip_bf16.h>

#define SEQLEN 2048
#define DMODEL 1024
#define INNER  2048
#define DSTATE 16
#define DTRANK 64
#define NPROJ  96    // valid rows of W_x; padded to 128
#define NPAD   128
#define CHUNK  32
#define NCH    64    // SEQLEN / CHUNK

typedef __attribute__((ext_vector_type(8))) short bf16x8;
typedef __attribute__((ext_vector_type(4))) float f32x4;

__device__ __forceinline__ float softplusf(float x) {
    return (x > 20.f) ? x : log1pf(__expf(x));
}
__device__ __forceinline__ unsigned short f2bf(float x) {
    unsigned u = __float_as_uint(x);
    return (unsigned short)((u + 0x7FFF + ((u >> 16) & 1)) >> 16);
}
__device__ __forceinline__ float bf2f(unsigned short x) {
    return __uint_as_float((unsigned)x << 16);
}
__device__ __forceinline__ void gload_lds16(const void* g, void* l) {
    __builtin_amdgcn_global_load_lds(
        (__attribute__((address_space(1))) const unsigned int*)g,
        (__attribute__((address_space(3))) unsigned int*)l,
        16, 0, 0);
}
__device__ __forceinline__ void cvt8(const float* __restrict__ in,
                                     unsigned short* __restrict__ out, int i) {
    float4 a = ((const float4*)in)[2 * i];
    float4 b = ((const float4*)in)[2 * i + 1];
    uint4 v;
    v.x = f2bf(a.x) | ((unsigned)f2bf(a.y) << 16);
    v.y = f2bf(a.z) | ((unsigned)f2bf(a.w) << 16);
    v.z = f2bf(b.x) | ((unsigned)f2bf(b.y) << 16);
    v.w = f2bf(b.z) | ((unsigned)f2bf(b.w) << 16);
    ((uint4*)out)[i] = v;
}

// One-shot conversion of all bf16 operands.
// Segments (8-elem units): hidden 262144 | W_in 524288 | W_out 262144 |
// W_dt 16384 | W_x padded 96->128 rows 32768.  Total 1097728 units.
__global__ __launch_bounds__(256)
void cvt_all(const float* __restrict__ hidden, const float* __restrict__ W_in,
             const float* __restrict__ W_out, const float* __restrict__ W_dt,
             const float* __restrict__ W_x,
             unsigned short* __restrict__ hid_b, unsigned short* __restrict__ Win_b,
             unsigned short* __restrict__ Wout_b, unsigned short* __restrict__ Wdt_b,
             unsigned short* __restrict__ Wx_b)
{
    int i = blockIdx.x * 256 + threadIdx.x;
    if (i < 262144) { cvt8(hidden, hid_b, i); return; }
    i -= 262144;
    if (i < 524288) { cvt8(W_in, Win_b, i); return; }
    i -= 524288;
    if (i < 262144) { cvt8(W_out, Wout_b, i); return; }
    i -= 262144;
    if (i < 16384)  { cvt8(W_dt, Wdt_b, i); return; }
    i -= 16384;
    if (i < 32768) {
        int row = i >> 8;              // 256 units per 2048-wide row
        if (row < NPROJ) cvt8(W_x, Wx_b, i);
        else ((uint4*)Wx_b)[i] = make_uint4(0, 0, 0, 0);
    }
}

// C = A @ B^T, bf16 MFMA, fp32 accum.  BK=64, involution LDS swizzle
// (linear gload_lds dest + chunk^(row&7) pre-swizzled global source + XOR'd
// ds_read), bijective XCD swizzle on (bx,by).  Requires gridDim.x*y % 8 == 0,
// K/kspan % 64 == 0, M % BM == 0, N % BN == 0.
// 256 thr = 4 waves 2x2; wave tile (BM/2)x(BN/2); 16x16x32 MFMA.
// EPI 0: fp32 C (+ blockIdx.z*zCstride for split-K partials).
// EPI 1: bf16 C.  EPI 2: bf16 C = softplus(acc + bias[col]).
template<int BM, int BN, int EPI>
__global__ __launch_bounds__(256)
void gemm_bf16(const unsigned short* __restrict__ A, const int lda,
               const unsigned short* __restrict__ B, const int ldb,
               void* __restrict__ Cv, const int ldc, const long long zCstride,
               const int K, const int kspan, const float* __restrict__ bias)
{
    constexpr int FM = BM / 32;
    constexpr int FN = BN / 32;
    __shared__ alignas(16) short As[BM * 64];
    __shared__ alignas(16) short Bs[BN * 64];

    const int tid  = threadIdx.x;
    const int wave = tid >> 6;
    const int lane = tid & 63;

    // XCD-aware bijective swizzle of the flattened (bx,by) index
    int bid = blockIdx.y * gridDim.x + blockIdx.x;
    const int q = (gridDim.x * gridDim.y) >> 3;
    bid = (bid & 7) * q + (bid >> 3);
    const int bx = bid % gridDim.x;
    const int by = bid / gridDim.x;

    const long long row0 = (long long)by * BM;
    const long long col0 = (long long)bx * BN;
    const int wm = (wave >> 1) * (BM / 2);
    const int wn = (wave & 1) * (BN / 2);
    const int kstart = blockIdx.z * kspan;
    const int kend   = min(K, kstart + kspan);

    f32x4 acc[FM][FN] = {};

    // staging: thread t -> LDS row t/8 (+32 per pass), chunk t&7 (linear,
    // byte addr = t*16), fetching GLOBAL chunk (t&7)^(row&7)
    const int srow   = tid >> 3;
    const int schunk = (tid & 7) ^ (srow & 7);
    const unsigned short* gA = A + (row0 + srow) * lda + schunk * 8;
    const unsigned short* gB = B + (col0 + srow) * ldb + schunk * 8;
    short* lA = &As[srow * 64 + (tid & 7) * 8];
    short* lB = &Bs[srow * 64 + (tid & 7) * 8];

    const int fr = lane & 15;
    const int hi = lane >> 4;
    const int rb = fr & 7;            // row&7 of every fragment row this lane reads

    for (int kt = kstart; kt < kend; kt += 64) {
#pragma unroll
        for (int r = 0; r < BM; r += 32)
            gload_lds16(gA + (long long)r * lda + kt, lA + r * 64);
#pragma unroll
        for (int r = 0; r < BN; r += 32)
            gload_lds16(gB + (long long)r * ldb + kt, lB + r * 64);
        __syncthreads();

#pragma unroll
        for (int half = 0; half < 2; ++half) {
            const int kc = (((half << 2) + hi) ^ rb) * 8;   // swizzled 16B chunk
            bf16x8 af[FM], bfr[FN];
#pragma unroll
            for (int mi = 0; mi < FM; ++mi)
                af[mi] = *(const bf16x8*)&As[(wm + mi * 16 + fr) * 64 + kc];
#pragma unroll
            for (int ni = 0; ni < FN; ++ni)
                bfr[ni] = *(const bf16x8*)&Bs[(wn + ni * 16 + fr) * 64 + kc];
#pragma unroll
            for (int mi = 0; mi < FM; ++mi)
#pragma unroll
                for (int ni = 0; ni < FN; ++ni)
                    acc[mi][ni] = __builtin_amdgcn_mfma_f32_16x16x32_bf16(
                        af[mi], bfr[ni], acc[mi][ni], 0, 0, 0);
        }
        __syncthreads();
    }

    const int cr = hi * 4;            // C/D: col=lane&15, row=(lane>>4)*4+reg
#pragma unroll
    for (int mi = 0; mi < FM; ++mi)
#pragma unroll
        for (int ni = 0; ni < FN; ++ni) {
            long long rbase = row0 + wm + mi * 16 + cr;
            long long col   = col0 + wn + ni * 16 + fr;
#pragma unroll
            for (int r = 0; r < 4; ++r) {
                long long idx = (rbase + r) * ldc + col;
                if (EPI == 0) {
                    ((float*)Cv)[(long long)blockIdx.z * zCstride + idx] = acc[mi][ni][r];
                } else if (EPI == 1) {
                    ((unsigned short*)Cv)[idx] = f2bf(acc[mi][ni][r]);
                } else {
                    ((unsigned short*)Cv)[idx] = f2bf(softplusf(acc[mi][ni][r] + bias[col]));
                }
            }
        }
}

// out[i] = p0[i] + p1[i]  (split-K=2 combine), float4 vectorized
__global__ __launch_bounds__(256)
void reduce_out(const float* __restrict__ part, float* __restrict__ out)
{
    int i = blockIdx.x * 256 + threadIdx.x;   // i < SEQLEN*DMODEL/4
    float4 a = ((const float4*)part)[i];
    float4 b = ((const float4*)part)[i + SEQLEN * DMODEL / 4];
    a.x += b.x; a.y += b.y; a.z += b.z; a.w += b.w;
    ((float4*)out)[i] = a;
}

// u = silu(causal depthwise conv(proj_bf16) + b) -> bf16 u_b, 4 channels/thread
__global__ __launch_bounds__(256)
void conv_silu_kernel(const unsigned short* __restrict__ xz_b, const float* __restrict__ cw,
                      const float* __restrict__ cb, unsigned short* __restrict__ u_b)
{
    int i = blockIdx.x * 256 + threadIdx.x;   // i < SEQLEN * 512
    int l  = i >> 9;
    int dq = i & 511;
    int d  = dq * 4;
    float4 wv[4];
#pragma unroll
    for (int k = 0; k < 4; ++k) wv[k] = ((const float4*)cw)[d + k];
    float4 acc = ((const float4*)cb)[dq];
#pragma unroll
    for (int j = 0; j < 4; ++j) {
        int ls = l - 3 + j;
        if (ls >= 0) {
            ushort4 x = *(const ushort4*)&xz_b[(long long)ls * 4096 + d];
            acc.x = fmaf(((const float*)&wv[0])[j], bf2f(x.x), acc.x);
            acc.y = fmaf(((const float*)&wv[1])[j], bf2f(x.y), acc.y);
            acc.z = fmaf(((const float*)&wv[2])[j], bf2f(x.z), acc.z);
            acc.w = fmaf(((const float*)&wv[3])[j], bf2f(x.w), acc.w);
        }
    }
    float4 r;
    r.x = acc.x / (1.f + __expf(-acc.x));
    r.y = acc.y / (1.f + __expf(-acc.y));
    r.z = acc.z / (1.f + __expf(-acc.z));
    r.w = acc.w / (1.f + __expf(-acc.w));
    uint2 p;
    p.x = f2bf(r.x) | ((unsigned)f2bf(r.y) << 16);
    p.y = f2bf(r.z) | ((unsigned)f2bf(r.w) << 16);
    ((uint2*)u_b)[i] = p;
}

// projt[i] = sum_z part[z][i]; emits fp32 projt and bf16 projt_b (i < 2048*128)
__global__ __launch_bounds__(256)
void reduce_part(const float* __restrict__ part, float* __restrict__ projt,
                 unsigned short* __restrict__ projt_b)
{
    int i = blockIdx.x * 256 + threadIdx.x;
    float s = 0.f;
#pragma unroll
    for (int z = 0; z < 8; ++z) s += part[(long long)z * SEQLEN * NPAD + i];
    projt[i] = s;
    projt_b[i] = f2bf(s);
}

// Phase 1: local chunk scans (h0=0) -> chunk-final states + per-chunk delta sums
__global__ __launch_bounds__(256)
void scan_phase1(const unsigned short* __restrict__ delta_bf,
                 const unsigned short* __restrict__ u_b,
                 const float* __restrict__ projt, const float* __restrict__ A_log,
                 float* __restrict__ Sloc, float* __restrict__ sumd)
{
    __shared__ float Bsh[CHUNK][16];
    const int d  = blockIdx.x * 256 + threadIdx.x;
    const int c  = blockIdx.y;
    const int l0 = c * CHUNK;
    for (int i = threadIdx.x; i < CHUNK * 16; i += 256) {
        int l = i >> 4, j = i & 15;
        Bsh[l][j] = projt[(l0 + l) * NPAD + DTRANK + j];
    }
    __syncthreads();

    float A2[DSTATE];
#pragma unroll
    for (int n = 0; n < DSTATE; ++n)
        A2[n] = -__expf(A_log[d * DSTATE + n]) * 1.4426950408889634f;

    float dl[CHUNK], du[CHUNK];
#pragma unroll
    for (int t = 0; t < CHUNK; ++t) {
        int l = l0 + t;
        float dv = bf2f(delta_bf[l * INNER + d]);
        dl[t] = dv;
        du[t] = dv * bf2f(u_b[l * INNER + d]);
    }

    float h[DSTATE];
#pragma unroll
    for (int n = 0; n < DSTATE; ++n) h[n] = 0.f;
    float sd = 0.f;

#pragma unroll
    for (int t = 0; t < CHUNK; ++t) {
        sd += dl[t];
#pragma unroll
        for (int n = 0; n < DSTATE; ++n) {
            float dA = exp2f(dl[t] * A2[n]);
            h[n] = fmaf(dA, h[n], du[t] * Bsh[t][n]);
        }
    }
#pragma unroll
    for (int n = 0; n < DSTATE; ++n)
        Sloc[(c * INNER + d) * DSTATE + n] = h[n];
    sumd[c * INNER + d] = sd;
}

// Phase 2 (in-place): S[c] chunk-final -> state at chunk start
__global__ __launch_bounds__(256)
void scan_phase2(float* __restrict__ S, const float* __restrict__ sumd,
                 const float* __restrict__ A_log)
{
    int i = blockIdx.x * 256 + threadIdx.x;   // i < INNER*DSTATE
    int d = i >> 4;
    float A2 = -__expf(A_log[i]) * 1.4426950408889634f;
    float H = 0.f;
#pragma unroll
    for (int c = 0; c < NCH; ++c) {
        float s = S[c * INNER * DSTATE + i];
        float P = exp2f(A2 * sumd[c * INNER + d]);
        S[c * INNER * DSTATE + i] = H;
        H = fmaf(P, H, s);
    }
}

// Phase 3: re-scan; y = (h.C + D*u) * silu(gate_bf16) -> bf16 y_b (ld=2048)
__global__ __launch_bounds__(256)
void scan_phase3(const unsigned short* __restrict__ delta_bf,
                 const unsigned short* __restrict__ u_b,
                 const float* __restrict__ projt, const float* __restrict__ A_log,
                 const float* __restrict__ Hinit, const unsigned short* __restrict__ xz_b,
                 const float* __restrict__ D_skip, unsigned short* __restrict__ ybf)
{
    __shared__ float BC[CHUNK][32];
    const int d  = blockIdx.x * 256 + threadIdx.x;
    const int c  = blockIdx.y;
    const int l0 = c * CHUNK;
    for (int i = threadIdx.x; i < CHUNK * 32; i += 256) {
        int l = i >> 5, j = i & 31;
        BC[l][j] = projt[(l0 + l) * NPAD + DTRANK + j];
    }
    __syncthreads();

    float A2[DSTATE];
#pragma unroll
    for (int n = 0; n < DSTATE; ++n)
        A2[n] = -__expf(A_log[d * DSTATE + n]) * 1.4426950408889634f;

    float dl[CHUNK], uv[CHUNK];
#pragma unroll
    for (int t = 0; t < CHUNK; ++t) {
        int l = l0 + t;
        dl[t] = bf2f(delta_bf[l * INNER + d]);
        uv[t] = bf2f(u_b[l * INNER + d]);
    }

    float h[DSTATE];
#pragma unroll
    for (int n = 0; n < DSTATE; ++n)
        h[n] = Hinit[(c * INNER + d) * DSTATE + n];
    const float Dd = D_skip[d];

#pragma unroll
    for (int t = 0; t < CHUNK; ++t) {
        int l = l0 + t;
        float du = dl[t] * uv[t];
        float y = 0.f;
#pragma unroll
        for (int n = 0; n < DSTATE; ++n) {
            float dA = exp2f(dl[t] * A2[n]);
            h[n] = fmaf(dA, h[n], du * BC[t][n]);
            y = fmaf(h[n], BC[t][16 + n], y);
        }
        float yv = fmaf(Dd, uv[t], y);
        float g = bf2f(xz_b[(long long)l * 4096 + 2048 + d]);
        float sg = g / (1.f + __expf(-g));
        ybf[l * INNER + d] = f2bf(yv * sg);
    }
}

extern "C" void kernel_launch(void* const* d_in, const int* in_sizes, int n_in,
                              void* d_out, int out_size, void* d_ws, size_t ws_size,
                              hipStream_t stream)
{
    const float* hidden  = (const float*)d_in[0];
    const float* W_in    = (const float*)d_in[1];
    const float* conv_w  = (const float*)d_in[2];
    const float* conv_b  = (const float*)d_in[3];
    const float* W_x     = (const float*)d_in[4];
    const float* W_dt    = (const float*)d_in[5];
    const float* dt_bias = (const float*)d_in[6];
    const float* A_log   = (const float*)d_in[7];
    const float* D_skip  = (const float*)d_in[8];
    const float* W_out   = (const float*)d_in[9];
    float* out = (float*)d_out;

    // workspace layout, ~78.4 MB total (proven ceiling 82.6 MB, round 4)
    char* base = (char*)d_ws;
    unsigned short* xz_b    = (unsigned short*)(base + 0);         // 16.78MB bf16 proj|gate
    unsigned short* hid_b   = (unsigned short*)(base + 16777216);  // 4.19MB (dead after GEMM1)
    unsigned short* Win_b   = (unsigned short*)(base + 20971520);  // 16.78MB (dead after GEMM1)
    unsigned short* u_b     = (unsigned short*)(base + 16777216);  // 8.39MB, aliases hid_b/Win_b head
    float*          part    = (float*)(base + 25165824);           // 8.39MB, aliases Win_b tail
    float*          Sloc    = (float*)(base + 25165824);           // aliases part after reduce
    unsigned short* dlt_b   = (unsigned short*)(base + 37748736);  // 8.39MB
    unsigned short* y_b     = (unsigned short*)(base + 46137344);  // 8.39MB
    float*          projt   = (float*)(base + 54525952);           // 1.05MB (2048 x 128)
    unsigned short* projt_b = (unsigned short*)(base + 55574528);  // 0.52MB
    unsigned short* Wout_b  = (unsigned short*)(base + 56098816);  // 4.19MB
    unsigned short* Wx_b    = (unsigned short*)(base + 60293120);  // 0.52MB (128 x 2048)
    unsigned short* Wdt_b   = (unsigned short*)(base + 60817408);  // 0.26MB
    float*          sumd    = (float*)(base + 61079552);           // 0.52MB
    float*          opart   = (float*)(base + 61603840);           // 16.78MB split-K partials

    // 0. all bf16 conversions in one dispatch (1097728 8-elem units)
    cvt_all<<<4289, 256, 0, stream>>>(hidden, W_in, W_out, W_dt, W_x,
                                      hid_b, Win_b, Wout_b, Wdt_b, Wx_b);

    // 1. xz = hidden @ W_in^T  (2048 x 4096, K=1024) bf16 MFMA -> bf16 out
    gemm_bf16<128, 128, 1><<<dim3(32, 16, 1), 256, 0, stream>>>(
        hid_b, DMODEL, Win_b, DMODEL, xz_b, 4096, 0, DMODEL, DMODEL, nullptr);

    // 2. u_b = silu(conv(proj_bf16) + b)  (bf16 only)
    conv_silu_kernel<<<SEQLEN * 512 / 256, 256, 0, stream>>>(xz_b, conv_w, conv_b, u_b);

    // 3. projt = u @ W_x^T  (2048 x 128pad, K=2048) bf16 MFMA split-K 8 + reduce
    gemm_bf16<128, 128, 0><<<dim3(1, 16, 8), 256, 0, stream>>>(
        u_b, INNER, Wx_b, INNER, part, NPAD, (long long)SEQLEN * NPAD,
        INNER, INNER / 8, nullptr);
    reduce_part<<<SEQLEN * NPAD / 256, 256, 0, stream>>>(part, projt, projt_b);

    // 4. delta = softplus(dt_lr @ W_dt^T + dt_bias) -> bf16  (2048 x 2048, K=64)
    gemm_bf16<128, 128, 2><<<dim3(16, 16, 1), 256, 0, stream>>>(
        projt_b, NPAD, Wdt_b, DTRANK, dlt_b, INNER, 0, DTRANK, DTRANK, dt_bias);

    // 5-7. chunked selective scan (CHUNK=32) + fused gated epilogue -> y_b
    scan_phase1<<<dim3(INNER / 256, NCH), 256, 0, stream>>>(dlt_b, u_b, projt, A_log, Sloc, sumd);
    scan_phase2<<<(INNER * DSTATE) / 256, 256, 0, stream>>>(Sloc, sumd, A_log);
    scan_phase3<<<dim3(INNER / 256, NCH), 256, 0, stream>>>(dlt_b, u_b, projt, A_log,
                                                            Sloc, xz_b, D_skip, y_b);

    // 8. out = y @ W_out^T  (2048 x 1024, K=2048) bf16 MFMA, split-K 2 + combine
    gemm_bf16<128, 64, 0><<<dim3(16, 16, 2), 256, 0, stream>>>(
        y_b, INNER, Wout_b, INNER, opart, DMODEL, (long long)SEQLEN * DMODEL,
        INNER, INNER / 2, nullptr);
    reduce_out<<<SEQLEN * DMODEL / 1024, 256, 0, stream>>>(opart, out);
}

// Round 8
// 170.612 us; speedup vs baseline: 4.1306x; 1.0140x over previous
//
#include <hip/hip_runtime.h>
#include <hip/hip_bf16.h>

#define SEQLEN 2048
#define DMODEL 1024
#define INNER  2048
#define DSTATE 16
#define DTRANK 64
#define NPROJ  96    // valid rows of W_x; padded to 128
#define NPAD   128
#define CHUNK  16
#define NCH    128   // SEQLEN / CHUNK
#define KSPLIT 16    // x-proj split-K ways

typedef __attribute__((ext_vector_type(8))) short bf16x8;
typedef __attribute__((ext_vector_type(4))) float f32x4;

__device__ __forceinline__ float softplusf(float x) {
    return (x > 20.f) ? x : log1pf(__expf(x));
}
__device__ __forceinline__ unsigned short f2bf(float x) {
    unsigned u = __float_as_uint(x);
    return (unsigned short)((u + 0x7FFF + ((u >> 16) & 1)) >> 16);
}
__device__ __forceinline__ float bf2f(unsigned short x) {
    return __uint_as_float((unsigned)x << 16);
}
__device__ __forceinline__ void gload_lds16(const void* g, void* l) {
    __builtin_amdgcn_global_load_lds(
        (__attribute__((address_space(1))) const unsigned int*)g,
        (__attribute__((address_space(3))) unsigned int*)l,
        16, 0, 0);
}
__device__ __forceinline__ void cvt8(const float* __restrict__ in,
                                     unsigned short* __restrict__ out, int i) {
    float4 a = ((const float4*)in)[2 * i];
    float4 b = ((const float4*)in)[2 * i + 1];
    uint4 v;
    v.x = f2bf(a.x) | ((unsigned)f2bf(a.y) << 16);
    v.y = f2bf(a.z) | ((unsigned)f2bf(a.w) << 16);
    v.z = f2bf(b.x) | ((unsigned)f2bf(b.y) << 16);
    v.w = f2bf(b.z) | ((unsigned)f2bf(b.w) << 16);
    ((uint4*)out)[i] = v;
}

// One-shot conversion of all bf16 operands.
// Segments (8-elem units): hidden 262144 | W_in 524288 | W_out 262144 |
// W_dt 16384 | W_x padded 96->128 rows 32768.  Total 1097728 units.
__global__ __launch_bounds__(256)
void cvt_all(const float* __restrict__ hidden, const float* __restrict__ W_in,
             const float* __restrict__ W_out, const float* __restrict__ W_dt,
             const float* __restrict__ W_x,
             unsigned short* __restrict__ hid_b, unsigned short* __restrict__ Win_b,
             unsigned short* __restrict__ Wout_b, unsigned short* __restrict__ Wdt_b,
             unsigned short* __restrict__ Wx_b)
{
    int i = blockIdx.x * 256 + threadIdx.x;
    if (i < 262144) { cvt8(hidden, hid_b, i); return; }
    i -= 262144;
    if (i < 524288) { cvt8(W_in, Win_b, i); return; }
    i -= 524288;
    if (i < 262144) { cvt8(W_out, Wout_b, i); return; }
    i -= 262144;
    if (i < 16384)  { cvt8(W_dt, Wdt_b, i); return; }
    i -= 16384;
    if (i < 32768) {
        int row = i >> 8;              // 256 units per 2048-wide row
        if (row < NPROJ) cvt8(W_x, Wx_b, i);
        else ((uint4*)Wx_b)[i] = make_uint4(0, 0, 0, 0);
    }
}

// C = A @ B^T, bf16 MFMA, fp32 accum.  BK=64, involution LDS swizzle
// (linear gload_lds dest + chunk^(row&7) pre-swizzled global source + XOR'd
// ds_read), bijective XCD swizzle on (bx,by).  Requires gridDim.x*y % 8 == 0,
// K/kspan % 64 == 0, M % BM == 0, N % BN == 0.
// 256 thr = 4 waves 2x2; wave tile (BM/2)x(BN/2); 16x16x32 MFMA.
// EPI 0: fp32 C (+ blockIdx.z*zCstride for split-K partials).
// EPI 1: bf16 C.  EPI 2: bf16 C = softplus(acc + bias[col]).
template<int BM, int BN, int EPI>
__global__ __launch_bounds__(256)
void gemm_bf16(const unsigned short* __restrict__ A, const int lda,
               const unsigned short* __restrict__ B, const int ldb,
               void* __restrict__ Cv, const int ldc, const long long zCstride,
               const int K, const int kspan, const float* __restrict__ bias)
{
    constexpr int FM = BM / 32;
    constexpr int FN = BN / 32;
    __shared__ alignas(16) short As[BM * 64];
    __shared__ alignas(16) short Bs[BN * 64];

    const int tid  = threadIdx.x;
    const int wave = tid >> 6;
    const int lane = tid & 63;

    // XCD-aware bijective swizzle of the flattened (bx,by) index
    int bid = blockIdx.y * gridDim.x + blockIdx.x;
    const int q = (gridDim.x * gridDim.y) >> 3;
    bid = (bid & 7) * q + (bid >> 3);
    const int bx = bid % gridDim.x;
    const int by = bid / gridDim.x;

    const long long row0 = (long long)by * BM;
    const long long col0 = (long long)bx * BN;
    const int wm = (wave >> 1) * (BM / 2);
    const int wn = (wave & 1) * (BN / 2);
    const int kstart = blockIdx.z * kspan;
    const int kend   = min(K, kstart + kspan);

    f32x4 acc[FM][FN] = {};

    // staging: thread t -> LDS row t/8 (+32 per pass), chunk t&7 (linear,
    // byte addr = t*16), fetching GLOBAL chunk (t&7)^(row&7)
    const int srow   = tid >> 3;
    const int schunk = (tid & 7) ^ (srow & 7);
    const unsigned short* gA = A + (row0 + srow) * lda + schunk * 8;
    const unsigned short* gB = B + (col0 + srow) * ldb + schunk * 8;
    short* lA = &As[srow * 64 + (tid & 7) * 8];
    short* lB = &Bs[srow * 64 + (tid & 7) * 8];

    const int fr = lane & 15;
    const int hi = lane >> 4;
    const int rb = fr & 7;            // row&7 of every fragment row this lane reads

    for (int kt = kstart; kt < kend; kt += 64) {
#pragma unroll
        for (int r = 0; r < BM; r += 32)
            gload_lds16(gA + (long long)r * lda + kt, lA + r * 64);
#pragma unroll
        for (int r = 0; r < BN; r += 32)
            gload_lds16(gB + (long long)r * ldb + kt, lB + r * 64);
        __syncthreads();

#pragma unroll
        for (int half = 0; half < 2; ++half) {
            const int kc = (((half << 2) + hi) ^ rb) * 8;   // swizzled 16B chunk
            bf16x8 af[FM], bfr[FN];
#pragma unroll
            for (int mi = 0; mi < FM; ++mi)
                af[mi] = *(const bf16x8*)&As[(wm + mi * 16 + fr) * 64 + kc];
#pragma unroll
            for (int ni = 0; ni < FN; ++ni)
                bfr[ni] = *(const bf16x8*)&Bs[(wn + ni * 16 + fr) * 64 + kc];
#pragma unroll
            for (int mi = 0; mi < FM; ++mi)
#pragma unroll
                for (int ni = 0; ni < FN; ++ni)
                    acc[mi][ni] = __builtin_amdgcn_mfma_f32_16x16x32_bf16(
                        af[mi], bfr[ni], acc[mi][ni], 0, 0, 0);
        }
        __syncthreads();
    }

    const int cr = hi * 4;            // C/D: col=lane&15, row=(lane>>4)*4+reg
#pragma unroll
    for (int mi = 0; mi < FM; ++mi)
#pragma unroll
        for (int ni = 0; ni < FN; ++ni) {
            long long rbase = row0 + wm + mi * 16 + cr;
            long long col   = col0 + wn + ni * 16 + fr;
#pragma unroll
            for (int r = 0; r < 4; ++r) {
                long long idx = (rbase + r) * ldc + col;
                if (EPI == 0) {
                    ((float*)Cv)[(long long)blockIdx.z * zCstride + idx] = acc[mi][ni][r];
                } else if (EPI == 1) {
                    ((unsigned short*)Cv)[idx] = f2bf(acc[mi][ni][r]);
                } else {
                    ((unsigned short*)Cv)[idx] = f2bf(softplusf(acc[mi][ni][r] + bias[col]));
                }
            }
        }
}

// out[i] = p0[i] + p1[i]  (split-K=2 combine), float4 vectorized
__global__ __launch_bounds__(256)
void reduce_out(const float* __restrict__ part, float* __restrict__ out)
{
    int i = blockIdx.x * 256 + threadIdx.x;   // i < SEQLEN*DMODEL/4
    float4 a = ((const float4*)part)[i];
    float4 b = ((const float4*)part)[i + SEQLEN * DMODEL / 4];
    a.x += b.x; a.y += b.y; a.z += b.z; a.w += b.w;
    ((float4*)out)[i] = a;
}

// u = silu(causal depthwise conv(proj_bf16) + b) -> bf16 u_b, 8 channels/thread
__global__ __launch_bounds__(256)
void conv_silu_kernel(const unsigned short* __restrict__ xz_b, const float* __restrict__ cw,
                      const float* __restrict__ cb, unsigned short* __restrict__ u_b)
{
    int i = blockIdx.x * 256 + threadIdx.x;   // i < SEQLEN * 256
    int l  = i >> 8;
    int dq = i & 255;
    int d  = dq * 8;
    float4 wv[8];
#pragma unroll
    for (int k = 0; k < 8; ++k) wv[k] = ((const float4*)cw)[d + k];
    float a[8];
    {
        float4 c0 = ((const float4*)cb)[dq * 2];
        float4 c1 = ((const float4*)cb)[dq * 2 + 1];
        a[0] = c0.x; a[1] = c0.y; a[2] = c0.z; a[3] = c0.w;
        a[4] = c1.x; a[5] = c1.y; a[6] = c1.z; a[7] = c1.w;
    }
#pragma unroll
    for (int j = 0; j < 4; ++j) {
        int ls = l - 3 + j;
        if (ls >= 0) {
            bf16x8 x = *(const bf16x8*)&xz_b[(long long)ls * 4096 + d];
#pragma unroll
            for (int k = 0; k < 8; ++k)
                a[k] = fmaf(((const float*)&wv[k])[j],
                            bf2f((unsigned short)x[k]), a[k]);
        }
    }
    uint4 p;
    float r[8];
#pragma unroll
    for (int k = 0; k < 8; ++k) r[k] = a[k] / (1.f + __expf(-a[k]));
    p.x = f2bf(r[0]) | ((unsigned)f2bf(r[1]) << 16);
    p.y = f2bf(r[2]) | ((unsigned)f2bf(r[3]) << 16);
    p.z = f2bf(r[4]) | ((unsigned)f2bf(r[5]) << 16);
    p.w = f2bf(r[6]) | ((unsigned)f2bf(r[7]) << 16);
    ((uint4*)u_b)[i] = p;
}

// projt[i] = sum_z part[z][i]; emits fp32 projt and bf16 projt_b (i < 2048*128)
__global__ __launch_bounds__(256)
void reduce_part(const float* __restrict__ part, float* __restrict__ projt,
                 unsigned short* __restrict__ projt_b)
{
    int i = blockIdx.x * 256 + threadIdx.x;
    float s = 0.f;
#pragma unroll
    for (int z = 0; z < KSPLIT; ++z) s += part[(long long)z * SEQLEN * NPAD + i];
    projt[i] = s;
    projt_b[i] = f2bf(s);
}

// Phase 1: local chunk scans (h0=0) -> chunk-final states + per-chunk delta sums
__global__ __launch_bounds__(256)
void scan_phase1(const unsigned short* __restrict__ delta_bf,
                 const unsigned short* __restrict__ u_b,
                 const float* __restrict__ projt, const float* __restrict__ A_log,
                 float* __restrict__ Sloc, float* __restrict__ sumd)
{
    __shared__ float Bsh[CHUNK][16];
    const int d  = blockIdx.x * 256 + threadIdx.x;
    const int c  = blockIdx.y;
    const int l0 = c * CHUNK;
    for (int i = threadIdx.x; i < CHUNK * 16; i += 256) {
        int l = i >> 4, j = i & 15;
        Bsh[l][j] = projt[(l0 + l) * NPAD + DTRANK + j];
    }
    __syncthreads();

    float A2[DSTATE];
#pragma unroll
    for (int n = 0; n < DSTATE; ++n)
        A2[n] = -__expf(A_log[d * DSTATE + n]) * 1.4426950408889634f;

    float dl[CHUNK], du[CHUNK];
#pragma unroll
    for (int t = 0; t < CHUNK; ++t) {
        int l = l0 + t;
        float dv = bf2f(delta_bf[l * INNER + d]);
        dl[t] = dv;
        du[t] = dv * bf2f(u_b[l * INNER + d]);
    }

    float h[DSTATE];
#pragma unroll
    for (int n = 0; n < DSTATE; ++n) h[n] = 0.f;
    float sd = 0.f;

#pragma unroll
    for (int t = 0; t < CHUNK; ++t) {
        sd += dl[t];
#pragma unroll
        for (int n = 0; n < DSTATE; ++n) {
            float dA = exp2f(dl[t] * A2[n]);
            h[n] = fmaf(dA, h[n], du[t] * Bsh[t][n]);
        }
    }
#pragma unroll
    for (int n = 0; n < DSTATE; ++n)
        Sloc[(c * INNER + d) * DSTATE + n] = h[n];
    sumd[c * INNER + d] = sd;
}

// Phase 2 (in-place): S[c] chunk-final -> state at chunk start
__global__ __launch_bounds__(256)
void scan_phase2(float* __restrict__ S, const float* __restrict__ sumd,
                 const float* __restrict__ A_log)
{
    int i = blockIdx.x * 256 + threadIdx.x;   // i < INNER*DSTATE
    int d = i >> 4;
    float A2 = -__expf(A_log[i]) * 1.4426950408889634f;
    float H = 0.f;
#pragma unroll
    for (int c = 0; c < NCH; ++c) {
        float s = S[c * (INNER * DSTATE) + i];
        float P = exp2f(A2 * sumd[c * INNER + d]);
        S[c * (INNER * DSTATE) + i] = H;
        H = fmaf(P, H, s);
    }
}

// Phase 3: re-scan; y = (h.C + D*u) * silu(gate_bf16) -> bf16 y_b (ld=2048)
__global__ __launch_bounds__(256)
void scan_phase3(const unsigned short* __restrict__ delta_bf,
                 const unsigned short* __restrict__ u_b,
                 const float* __restrict__ projt, const float* __restrict__ A_log,
                 const float* __restrict__ Hinit, const unsigned short* __restrict__ xz_b,
                 const float* __restrict__ D_skip, unsigned short* __restrict__ ybf)
{
    __shared__ float BC[CHUNK][32];
    const int d  = blockIdx.x * 256 + threadIdx.x;
    const int c  = blockIdx.y;
    const int l0 = c * CHUNK;
    for (int i = threadIdx.x; i < CHUNK * 32; i += 256) {
        int l = i >> 5, j = i & 31;
        BC[l][j] = projt[(l0 + l) * NPAD + DTRANK + j];
    }
    __syncthreads();

    float A2[DSTATE];
#pragma unroll
    for (int n = 0; n < DSTATE; ++n)
        A2[n] = -__expf(A_log[d * DSTATE + n]) * 1.4426950408889634f;

    float dl[CHUNK], uv[CHUNK];
#pragma unroll
    for (int t = 0; t < CHUNK; ++t) {
        int l = l0 + t;
        dl[t] = bf2f(delta_bf[l * INNER + d]);
        uv[t] = bf2f(u_b[l * INNER + d]);
    }

    float h[DSTATE];
#pragma unroll
    for (int n = 0; n < DSTATE; ++n)
        h[n] = Hinit[(c * INNER + d) * DSTATE + n];
    const float Dd = D_skip[d];

#pragma unroll
    for (int t = 0; t < CHUNK; ++t) {
        int l = l0 + t;
        float du = dl[t] * uv[t];
        float y = 0.f;
#pragma unroll
        for (int n = 0; n < DSTATE; ++n) {
            float dA = exp2f(dl[t] * A2[n]);
            h[n] = fmaf(dA, h[n], du * BC[t][n]);
            y = fmaf(h[n], BC[t][16 + n], y);
        }
        float yv = fmaf(Dd, uv[t], y);
        float g = bf2f(xz_b[(long long)l * 4096 + 2048 + d]);
        float sg = g / (1.f + __expf(-g));
        ybf[l * INNER + d] = f2bf(yv * sg);
    }
}

extern "C" void kernel_launch(void* const* d_in, const int* in_sizes, int n_in,
                              void* d_out, int out_size, void* d_ws, size_t ws_size,
                              hipStream_t stream)
{
    const float* hidden  = (const float*)d_in[0];
    const float* W_in    = (const float*)d_in[1];
    const float* conv_w  = (const float*)d_in[2];
    const float* conv_b  = (const float*)d_in[3];
    const float* W_x     = (const float*)d_in[4];
    const float* W_dt    = (const float*)d_in[5];
    const float* dt_bias = (const float*)d_in[6];
    const float* A_log   = (const float*)d_in[7];
    const float* D_skip  = (const float*)d_in[8];
    const float* W_out   = (const float*)d_in[9];
    float* out = (float*)d_out;

    // workspace layout, 66.3 MB total (proven ceiling 82.6 MB, round 4).
    // Triple-aliased slot [25165824, 41943040): part16 (xproj->reduce),
    // then Sloc (scan1->scan3), then opart (outGEMM->reduce_out).
    char* base = (char*)d_ws;
    unsigned short* xz_b    = (unsigned short*)(base + 0);         // 16.78MB bf16 proj|gate
    unsigned short* hid_b   = (unsigned short*)(base + 16777216);  // pre-GEMM1 only
    unsigned short* Win_b   = (unsigned short*)(base + 20971520);  // pre-GEMM1 only (ends 37748736)
    unsigned short* u_b     = (unsigned short*)(base + 16777216);  // 8.39MB (conv onward)
    float*          part16  = (float*)(base + 25165824);           // 16.78MB split-K partials
    float*          Sloc    = (float*)(base + 25165824);           // 16.78MB (aliases part16)
    float*          opart   = (float*)(base + 25165824);           // 16.78MB (aliases Sloc)
    unsigned short* dlt_b   = (unsigned short*)(base + 41943040);  // 8.39MB
    unsigned short* y_b     = (unsigned short*)(base + 50331648);  // 8.39MB
    float*          projt   = (float*)(base + 58720256);           // 1.05MB (2048 x 128)
    unsigned short* projt_b = (unsigned short*)(base + 59768832);  // 0.52MB
    unsigned short* Wout_b  = (unsigned short*)(base + 60293120);  // 4.19MB
    unsigned short* Wx_b    = (unsigned short*)(base + 64487424);  // 0.52MB (128 x 2048)
    unsigned short* Wdt_b   = (unsigned short*)(base + 65011712);  // 0.26MB
    float*          sumd    = (float*)(base + 65273856);           // 1.05MB (128 x 2048)

    // 0. all bf16 conversions in one dispatch (1097728 8-elem units)
    cvt_all<<<4289, 256, 0, stream>>>(hidden, W_in, W_out, W_dt, W_x,
                                      hid_b, Win_b, Wout_b, Wdt_b, Wx_b);

    // 1. xz = hidden @ W_in^T  (2048 x 4096, K=1024) bf16 MFMA -> bf16 out
    gemm_bf16<128, 128, 1><<<dim3(32, 16, 1), 256, 0, stream>>>(
        hid_b, DMODEL, Win_b, DMODEL, xz_b, 4096, 0, DMODEL, DMODEL, nullptr);

    // 2. u_b = silu(conv(proj_bf16) + b)  (bf16, 8 channels/thread)
    conv_silu_kernel<<<SEQLEN * 256 / 256, 256, 0, stream>>>(xz_b, conv_w, conv_b, u_b);

    // 3. projt = u @ W_x^T  (2048 x 128pad, K=2048) bf16 MFMA split-K 16 + reduce
    gemm_bf16<128, 128, 0><<<dim3(1, 16, KSPLIT), 256, 0, stream>>>(
        u_b, INNER, Wx_b, INNER, part16, NPAD, (long long)SEQLEN * NPAD,
        INNER, INNER / KSPLIT, nullptr);
    reduce_part<<<SEQLEN * NPAD / 256, 256, 0, stream>>>(part16, projt, projt_b);

    // 4. delta = softplus(dt_lr @ W_dt^T + dt_bias) -> bf16  (2048 x 2048, K=64)
    //    BN=64 -> 512 blocks (2/CU) for the single-K-pass latency-bound GEMM
    gemm_bf16<128, 64, 2><<<dim3(32, 16, 1), 256, 0, stream>>>(
        projt_b, NPAD, Wdt_b, DTRANK, dlt_b, INNER, 0, DTRANK, DTRANK, dt_bias);

    // 5-7. chunked selective scan (CHUNK=16, 1024 blocks/phase) + fused epilogue
    scan_phase1<<<dim3(INNER / 256, NCH), 256, 0, stream>>>(dlt_b, u_b, projt, A_log, Sloc, sumd);
    scan_phase2<<<(INNER * DSTATE) / 256, 256, 0, stream>>>(Sloc, sumd, A_log);
    scan_phase3<<<dim3(INNER / 256, NCH), 256, 0, stream>>>(dlt_b, u_b, projt, A_log,
                                                            Sloc, xz_b, D_skip, y_b);

    // 8. out = y @ W_out^T  (2048 x 1024, K=2048) bf16 MFMA, split-K 2 + combine
    gemm_bf16<128, 64, 0><<<dim3(16, 16, 2), 256, 0, stream>>>(
        y_b, INNER, Wout_b, INNER, opart, DMODEL, (long long)SEQLEN * DMODEL,
        INNER, INNER / 2, nullptr);
    reduce_out<<<SEQLEN * DMODEL / 1024, 256, 0, stream>>>(opart, out);
}

// Round 9
// 161.086 us; speedup vs baseline: 4.3749x; 1.0591x over previous
//
#include <hip/hip_runtime.h>
#include <hip/hip_bf16.h>

#define SEQLEN 2048
#define DMODEL 1024
#define INNER  2048
#define DSTATE 16
#define DTRANK 64
#define NPROJ  96    // valid rows of W_x; padded to 128
#define NPAD   128
#define CHUNK  16
#define NCH    128   // SEQLEN / CHUNK
#define KSPLIT 16    // x-proj split-K ways

typedef __attribute__((ext_vector_type(8))) short bf16x8;
typedef __attribute__((ext_vector_type(4))) float f32x4;

__device__ __forceinline__ float softplusf(float x) {
    return (x > 20.f) ? x : log1pf(__expf(x));
}
__device__ __forceinline__ unsigned short f2bf(float x) {
    unsigned u = __float_as_uint(x);
    return (unsigned short)((u + 0x7FFF + ((u >> 16) & 1)) >> 16);
}
__device__ __forceinline__ float bf2f(unsigned short x) {
    return __uint_as_float((unsigned)x << 16);
}
__device__ __forceinline__ void gload_lds16(const void* g, void* l) {
    __builtin_amdgcn_global_load_lds(
        (__attribute__((address_space(1))) const unsigned int*)g,
        (__attribute__((address_space(3))) unsigned int*)l,
        16, 0, 0);
}
__device__ __forceinline__ void cvt8(const float* __restrict__ in,
                                     unsigned short* __restrict__ out, int i) {
    float4 a = ((const float4*)in)[2 * i];
    float4 b = ((const float4*)in)[2 * i + 1];
    uint4 v;
    v.x = f2bf(a.x) | ((unsigned)f2bf(a.y) << 16);
    v.y = f2bf(a.z) | ((unsigned)f2bf(a.w) << 16);
    v.z = f2bf(b.x) | ((unsigned)f2bf(b.y) << 16);
    v.w = f2bf(b.z) | ((unsigned)f2bf(b.w) << 16);
    ((uint4*)out)[i] = v;
}

// One-shot conversion of all bf16 operands.
// Segments (8-elem units): hidden 262144 | W_in 524288 | W_out 262144 |
// W_dt 16384 | W_x padded 96->128 rows 32768.  Total 1097728 units.
__global__ __launch_bounds__(256)
void cvt_all(const float* __restrict__ hidden, const float* __restrict__ W_in,
             const float* __restrict__ W_out, const float* __restrict__ W_dt,
             const float* __restrict__ W_x,
             unsigned short* __restrict__ hid_b, unsigned short* __restrict__ Win_b,
             unsigned short* __restrict__ Wout_b, unsigned short* __restrict__ Wdt_b,
             unsigned short* __restrict__ Wx_b)
{
    int i = blockIdx.x * 256 + threadIdx.x;
    if (i < 262144) { cvt8(hidden, hid_b, i); return; }
    i -= 262144;
    if (i < 524288) { cvt8(W_in, Win_b, i); return; }
    i -= 524288;
    if (i < 262144) { cvt8(W_out, Wout_b, i); return; }
    i -= 262144;
    if (i < 16384)  { cvt8(W_dt, Wdt_b, i); return; }
    i -= 16384;
    if (i < 32768) {
        int row = i >> 8;              // 256 units per 2048-wide row
        if (row < NPROJ) cvt8(W_x, Wx_b, i);
        else ((uint4*)Wx_b)[i] = make_uint4(0, 0, 0, 0);
    }
}

// C = A @ B^T, bf16 MFMA, fp32 accum.  BK=64, involution LDS swizzle
// (linear gload_lds dest + chunk^(row&7) pre-swizzled global source + XOR'd
// ds_read), bijective XCD swizzle on (bx,by).  Requires gridDim.x*y % 8 == 0,
// K/kspan % 64 == 0, M % BM == 0, N % BN == 0.
// 256 thr = 4 waves 2x2; wave tile (BM/2)x(BN/2); 16x16x32 MFMA.
// EPI 0: fp32 C (+ blockIdx.z*zCstride for split-K partials).
// EPI 1: bf16 C.  EPI 2: bf16 C = softplus(acc + bias[col]).
template<int BM, int BN, int EPI>
__global__ __launch_bounds__(256)
void gemm_bf16(const unsigned short* __restrict__ A, const int lda,
               const unsigned short* __restrict__ B, const int ldb,
               void* __restrict__ Cv, const int ldc, const long long zCstride,
               const int K, const int kspan, const float* __restrict__ bias)
{
    constexpr int FM = BM / 32;
    constexpr int FN = BN / 32;
    __shared__ alignas(16) short As[BM * 64];
    __shared__ alignas(16) short Bs[BN * 64];

    const int tid  = threadIdx.x;
    const int wave = tid >> 6;
    const int lane = tid & 63;

    // XCD-aware bijective swizzle of the flattened (bx,by) index
    int bid = blockIdx.y * gridDim.x + blockIdx.x;
    const int q = (gridDim.x * gridDim.y) >> 3;
    bid = (bid & 7) * q + (bid >> 3);
    const int bx = bid % gridDim.x;
    const int by = bid / gridDim.x;

    const long long row0 = (long long)by * BM;
    const long long col0 = (long long)bx * BN;
    const int wm = (wave >> 1) * (BM / 2);
    const int wn = (wave & 1) * (BN / 2);
    const int kstart = blockIdx.z * kspan;
    const int kend   = min(K, kstart + kspan);

    f32x4 acc[FM][FN] = {};

    // staging: thread t -> LDS row t/8 (+32 per pass), chunk t&7 (linear,
    // byte addr = t*16), fetching GLOBAL chunk (t&7)^(row&7)
    const int srow   = tid >> 3;
    const int schunk = (tid & 7) ^ (srow & 7);
    const unsigned short* gA = A + (row0 + srow) * lda + schunk * 8;
    const unsigned short* gB = B + (col0 + srow) * ldb + schunk * 8;
    short* lA = &As[srow * 64 + (tid & 7) * 8];
    short* lB = &Bs[srow * 64 + (tid & 7) * 8];

    const int fr = lane & 15;
    const int hi = lane >> 4;
    const int rb = fr & 7;            // row&7 of every fragment row this lane reads

    for (int kt = kstart; kt < kend; kt += 64) {
#pragma unroll
        for (int r = 0; r < BM; r += 32)
            gload_lds16(gA + (long long)r * lda + kt, lA + r * 64);
#pragma unroll
        for (int r = 0; r < BN; r += 32)
            gload_lds16(gB + (long long)r * ldb + kt, lB + r * 64);
        __syncthreads();

#pragma unroll
        for (int half = 0; half < 2; ++half) {
            const int kc = (((half << 2) + hi) ^ rb) * 8;   // swizzled 16B chunk
            bf16x8 af[FM], bfr[FN];
#pragma unroll
            for (int mi = 0; mi < FM; ++mi)
                af[mi] = *(const bf16x8*)&As[(wm + mi * 16 + fr) * 64 + kc];
#pragma unroll
            for (int ni = 0; ni < FN; ++ni)
                bfr[ni] = *(const bf16x8*)&Bs[(wn + ni * 16 + fr) * 64 + kc];
#pragma unroll
            for (int mi = 0; mi < FM; ++mi)
#pragma unroll
                for (int ni = 0; ni < FN; ++ni)
                    acc[mi][ni] = __builtin_amdgcn_mfma_f32_16x16x32_bf16(
                        af[mi], bfr[ni], acc[mi][ni], 0, 0, 0);
        }
        __syncthreads();
    }

    const int cr = hi * 4;            // C/D: col=lane&15, row=(lane>>4)*4+reg
#pragma unroll
    for (int mi = 0; mi < FM; ++mi)
#pragma unroll
        for (int ni = 0; ni < FN; ++ni) {
            long long rbase = row0 + wm + mi * 16 + cr;
            long long col   = col0 + wn + ni * 16 + fr;
#pragma unroll
            for (int r = 0; r < 4; ++r) {
                long long idx = (rbase + r) * ldc + col;
                if (EPI == 0) {
                    ((float*)Cv)[(long long)blockIdx.z * zCstride + idx] = acc[mi][ni][r];
                } else if (EPI == 1) {
                    ((unsigned short*)Cv)[idx] = f2bf(acc[mi][ni][r]);
                } else {
                    ((unsigned short*)Cv)[idx] = f2bf(softplusf(acc[mi][ni][r] + bias[col]));
                }
            }
        }
}

// Fused conv+silu+x-proj GEMM: part[z] = u_patch @ Wx^T where
// u = silu(depthwise_conv(xz_proj) + cb) is computed IN the A-staging from
// xz_b and also written to u_b (each (l,d) exactly once: z partitions the
// channel/K dim, by partitions rows).  u_b values are bit-identical to the
// old conv kernel's (same math, same bf16 rounding).  BM=BN=128, BK=64,
// kspan=128, grid (1,16,KSPLIT); same swizzles/epilogue as gemm_bf16 EPI=0.
__global__ __launch_bounds__(256)
void xproj_fused(const unsigned short* __restrict__ xz_b,
                 const float* __restrict__ cw, const float* __restrict__ cb,
                 const unsigned short* __restrict__ Wx_b,
                 unsigned short* __restrict__ u_b, float* __restrict__ Cv)
{
    __shared__ alignas(16) short As[128 * 64];
    __shared__ alignas(16) short Bs[128 * 64];

    const int tid  = threadIdx.x;
    const int wave = tid >> 6;
    const int lane = tid & 63;

    int bid = blockIdx.y;                  // gridDim.x == 1, 16 blocks in y
    bid = (bid & 7) * 2 + (bid >> 3);      // bijective XCD swizzle (q=2)
    const long long row0 = (long long)bid * 128;

    const int wm = (wave >> 1) * 64;
    const int wn = (wave & 1) * 64;
    const int kstart = blockIdx.z * (INNER / KSPLIT);   // 128-channel span

    f32x4 acc[2][2] = {};

    const int srow   = tid >> 3;
    const int gchunk = (tid & 7) ^ (srow & 7);
    short* lA = &As[srow * 64 + (tid & 7) * 8];
    short* lB = &Bs[srow * 64 + (tid & 7) * 8];
    const unsigned short* gB = Wx_b + srow * INNER + gchunk * 8;

    const int fr = lane & 15;
    const int hi = lane >> 4;
    const int rb = fr & 7;

    for (int kt = kstart; kt < kstart + 128; kt += 64) {
        const int d = kt + gchunk * 8;     // my 8 channels this K-tile
        float4 wv[8];
#pragma unroll
        for (int k = 0; k < 8; ++k) wv[k] = ((const float4*)cw)[d + k];
        float bias8[8];
        {
            float4 c0 = ((const float4*)cb)[d >> 2];
            float4 c1 = ((const float4*)cb)[(d >> 2) + 1];
            bias8[0] = c0.x; bias8[1] = c0.y; bias8[2] = c0.z; bias8[3] = c0.w;
            bias8[4] = c1.x; bias8[5] = c1.y; bias8[6] = c1.z; bias8[7] = c1.w;
        }
#pragma unroll
        for (int r = 0; r < 128; r += 32) {
            const long long l = row0 + srow + r;
            float a[8];
#pragma unroll
            for (int k = 0; k < 8; ++k) a[k] = bias8[k];
#pragma unroll
            for (int j = 0; j < 4; ++j) {
                long long ls = l - 3 + j;
                if (ls >= 0) {
                    bf16x8 x = *(const bf16x8*)&xz_b[ls * 4096 + d];
#pragma unroll
                    for (int k = 0; k < 8; ++k)
                        a[k] = fmaf(((const float*)&wv[k])[j],
                                    bf2f((unsigned short)x[k]), a[k]);
                }
            }
            float s8[8];
#pragma unroll
            for (int k = 0; k < 8; ++k) s8[k] = a[k] / (1.f + __expf(-a[k]));
            uint4 p;
            p.x = f2bf(s8[0]) | ((unsigned)f2bf(s8[1]) << 16);
            p.y = f2bf(s8[2]) | ((unsigned)f2bf(s8[3]) << 16);
            p.z = f2bf(s8[4]) | ((unsigned)f2bf(s8[5]) << 16);
            p.w = f2bf(s8[6]) | ((unsigned)f2bf(s8[7]) << 16);
            *(uint4*)(lA + r * 64) = p;                 // swizzled LDS slot
            *(uint4*)&u_b[l * INNER + d] = p;           // global u (once)
        }
#pragma unroll
        for (int r = 0; r < 128; r += 32)
            gload_lds16(gB + (long long)r * INNER + kt, lB + r * 64);
        __syncthreads();

#pragma unroll
        for (int half = 0; half < 2; ++half) {
            const int kc = (((half << 2) + hi) ^ rb) * 8;
            bf16x8 af[2], bfr[2];
#pragma unroll
            for (int mi = 0; mi < 2; ++mi)
                af[mi] = *(const bf16x8*)&As[(wm + mi * 16 + fr) * 64 + kc];
#pragma unroll
            for (int ni = 0; ni < 2; ++ni)
                bfr[ni] = *(const bf16x8*)&Bs[(wn + ni * 16 + fr) * 64 + kc];
#pragma unroll
            for (int mi = 0; mi < 2; ++mi)
#pragma unroll
                for (int ni = 0; ni < 2; ++ni)
                    acc[mi][ni] = __builtin_amdgcn_mfma_f32_16x16x32_bf16(
                        af[mi], bfr[ni], acc[mi][ni], 0, 0, 0);
        }
        __syncthreads();
    }

    const int cr = hi * 4;
#pragma unroll
    for (int mi = 0; mi < 2; ++mi)
#pragma unroll
        for (int ni = 0; ni < 2; ++ni) {
            long long rbase = row0 + wm + mi * 16 + cr;
            long long col   = wn + ni * 16 + fr;
#pragma unroll
            for (int r = 0; r < 4; ++r)
                Cv[(long long)blockIdx.z * (SEQLEN * NPAD) +
                   (rbase + r) * NPAD + col] = acc[mi][ni][r];
        }
}

// out[i] = p0[i] + p1[i]  (split-K=2 combine), float4 vectorized
__global__ __launch_bounds__(256)
void reduce_out(const float* __restrict__ part, float* __restrict__ out)
{
    int i = blockIdx.x * 256 + threadIdx.x;   // i < SEQLEN*DMODEL/4
    float4 a = ((const float4*)part)[i];
    float4 b = ((const float4*)part)[i + SEQLEN * DMODEL / 4];
    a.x += b.x; a.y += b.y; a.z += b.z; a.w += b.w;
    ((float4*)out)[i] = a;
}

// projt[i] = sum_z part[z][i]; emits fp32 projt and bf16 projt_b (i < 2048*128)
__global__ __launch_bounds__(256)
void reduce_part(const float* __restrict__ part, float* __restrict__ projt,
                 unsigned short* __restrict__ projt_b)
{
    int i = blockIdx.x * 256 + threadIdx.x;
    float s = 0.f;
#pragma unroll
    for (int z = 0; z < KSPLIT; ++z) s += part[(long long)z * SEQLEN * NPAD + i];
    projt[i] = s;
    projt_b[i] = f2bf(s);
}

// Phase 1: local chunk scans (h0=0) -> bf16 chunk-final states + delta sums
__global__ __launch_bounds__(256)
void scan_phase1(const unsigned short* __restrict__ delta_bf,
                 const unsigned short* __restrict__ u_b,
                 const float* __restrict__ projt, const float* __restrict__ A_log,
                 unsigned short* __restrict__ Slocb, float* __restrict__ sumd)
{
    __shared__ float Bsh[CHUNK][16];
    const int d  = blockIdx.x * 256 + threadIdx.x;
    const int c  = blockIdx.y;
    const int l0 = c * CHUNK;
    for (int i = threadIdx.x; i < CHUNK * 16; i += 256) {
        int l = i >> 4, j = i & 15;
        Bsh[l][j] = projt[(l0 + l) * NPAD + DTRANK + j];
    }
    __syncthreads();

    float A2[DSTATE];
#pragma unroll
    for (int n = 0; n < DSTATE; ++n)
        A2[n] = -__expf(A_log[d * DSTATE + n]) * 1.4426950408889634f;

    float dl[CHUNK], du[CHUNK];
#pragma unroll
    for (int t = 0; t < CHUNK; ++t) {
        int l = l0 + t;
        float dv = bf2f(delta_bf[l * INNER + d]);
        dl[t] = dv;
        du[t] = dv * bf2f(u_b[l * INNER + d]);
    }

    float h[DSTATE];
#pragma unroll
    for (int n = 0; n < DSTATE; ++n) h[n] = 0.f;
    float sd = 0.f;

#pragma unroll
    for (int t = 0; t < CHUNK; ++t) {
        sd += dl[t];
#pragma unroll
        for (int n = 0; n < DSTATE; ++n) {
            float dA = exp2f(dl[t] * A2[n]);
            h[n] = fmaf(dA, h[n], du[t] * Bsh[t][n]);
        }
    }
    uint4 p0, p1;
    p0.x = f2bf(h[0])  | ((unsigned)f2bf(h[1])  << 16);
    p0.y = f2bf(h[2])  | ((unsigned)f2bf(h[3])  << 16);
    p0.z = f2bf(h[4])  | ((unsigned)f2bf(h[5])  << 16);
    p0.w = f2bf(h[6])  | ((unsigned)f2bf(h[7])  << 16);
    p1.x = f2bf(h[8])  | ((unsigned)f2bf(h[9])  << 16);
    p1.y = f2bf(h[10]) | ((unsigned)f2bf(h[11]) << 16);
    p1.z = f2bf(h[12]) | ((unsigned)f2bf(h[13]) << 16);
    p1.w = f2bf(h[14]) | ((unsigned)f2bf(h[15]) << 16);
    uint4* dst = (uint4*)&Slocb[(long long)(c * INNER + d) * DSTATE];
    dst[0] = p0; dst[1] = p1;
    sumd[c * INNER + d] = sd;
}

// Phase 2 (in-place, bf16 state): S[c] chunk-final -> state at chunk start
__global__ __launch_bounds__(256)
void scan_phase2(unsigned short* __restrict__ S, const float* __restrict__ sumd,
                 const float* __restrict__ A_log)
{
    int i = blockIdx.x * 256 + threadIdx.x;   // i < INNER*DSTATE
    int d = i >> 4;
    float A2 = -__expf(A_log[i]) * 1.4426950408889634f;
    float H = 0.f;
#pragma unroll
    for (int c = 0; c < NCH; ++c) {
        float s = bf2f(S[c * (INNER * DSTATE) + i]);
        float P = exp2f(A2 * sumd[c * INNER + d]);
        S[c * (INNER * DSTATE) + i] = f2bf(H);
        H = fmaf(P, H, s);
    }
}

// Phase 3: re-scan from bf16 Hinit; y = (h.C + D*u) * silu(gate) -> bf16 y_b
__global__ __launch_bounds__(256)
void scan_phase3(const unsigned short* __restrict__ delta_bf,
                 const unsigned short* __restrict__ u_b,
                 const float* __restrict__ projt, const float* __restrict__ A_log,
                 const unsigned short* __restrict__ Hinit,
                 const unsigned short* __restrict__ xz_b,
                 const float* __restrict__ D_skip, unsigned short* __restrict__ ybf)
{
    __shared__ float BC[CHUNK][32];
    const int d  = blockIdx.x * 256 + threadIdx.x;
    const int c  = blockIdx.y;
    const int l0 = c * CHUNK;
    for (int i = threadIdx.x; i < CHUNK * 32; i += 256) {
        int l = i >> 5, j = i & 31;
        BC[l][j] = projt[(l0 + l) * NPAD + DTRANK + j];
    }
    __syncthreads();

    float A2[DSTATE];
#pragma unroll
    for (int n = 0; n < DSTATE; ++n)
        A2[n] = -__expf(A_log[d * DSTATE + n]) * 1.4426950408889634f;

    float dl[CHUNK], uv[CHUNK];
#pragma unroll
    for (int t = 0; t < CHUNK; ++t) {
        int l = l0 + t;
        dl[t] = bf2f(delta_bf[l * INNER + d]);
        uv[t] = bf2f(u_b[l * INNER + d]);
    }

    float h[DSTATE];
    {
        const uint4* hp = (const uint4*)&Hinit[(long long)(c * INNER + d) * DSTATE];
        uint4 p0 = hp[0], p1 = hp[1];
        h[0]  = bf2f((unsigned short)(p0.x & 0xffff)); h[1]  = bf2f((unsigned short)(p0.x >> 16));
        h[2]  = bf2f((unsigned short)(p0.y & 0xffff)); h[3]  = bf2f((unsigned short)(p0.y >> 16));
        h[4]  = bf2f((unsigned short)(p0.z & 0xffff)); h[5]  = bf2f((unsigned short)(p0.z >> 16));
        h[6]  = bf2f((unsigned short)(p0.w & 0xffff)); h[7]  = bf2f((unsigned short)(p0.w >> 16));
        h[8]  = bf2f((unsigned short)(p1.x & 0xffff)); h[9]  = bf2f((unsigned short)(p1.x >> 16));
        h[10] = bf2f((unsigned short)(p1.y & 0xffff)); h[11] = bf2f((unsigned short)(p1.y >> 16));
        h[12] = bf2f((unsigned short)(p1.z & 0xffff)); h[13] = bf2f((unsigned short)(p1.z >> 16));
        h[14] = bf2f((unsigned short)(p1.w & 0xffff)); h[15] = bf2f((unsigned short)(p1.w >> 16));
    }
    const float Dd = D_skip[d];

#pragma unroll
    for (int t = 0; t < CHUNK; ++t) {
        int l = l0 + t;
        float du = dl[t] * uv[t];
        float y = 0.f;
#pragma unroll
        for (int n = 0; n < DSTATE; ++n) {
            float dA = exp2f(dl[t] * A2[n]);
            h[n] = fmaf(dA, h[n], du * BC[t][n]);
            y = fmaf(h[n], BC[t][16 + n], y);
        }
        float yv = fmaf(Dd, uv[t], y);
        float g = bf2f(xz_b[(long long)l * 4096 + 2048 + d]);
        float sg = g / (1.f + __expf(-g));
        ybf[l * INNER + d] = f2bf(yv * sg);
    }
}

extern "C" void kernel_launch(void* const* d_in, const int* in_sizes, int n_in,
                              void* d_out, int out_size, void* d_ws, size_t ws_size,
                              hipStream_t stream)
{
    const float* hidden  = (const float*)d_in[0];
    const float* W_in    = (const float*)d_in[1];
    const float* conv_w  = (const float*)d_in[2];
    const float* conv_b  = (const float*)d_in[3];
    const float* W_x     = (const float*)d_in[4];
    const float* W_dt    = (const float*)d_in[5];
    const float* dt_bias = (const float*)d_in[6];
    const float* A_log   = (const float*)d_in[7];
    const float* D_skip  = (const float*)d_in[8];
    const float* W_out   = (const float*)d_in[9];
    float* out = (float*)d_out;

    // workspace layout, 66.3 MB total (proven ceiling 82.6 MB, round 4).
    // Triple-aliased slot [25165824, 41943040): part16 (xproj->reduce),
    // then Slocb bf16 (scan1->scan3), then opart (outGEMM->reduce_out).
    char* base = (char*)d_ws;
    unsigned short* xz_b    = (unsigned short*)(base + 0);         // 16.78MB bf16 proj|gate
    unsigned short* hid_b   = (unsigned short*)(base + 16777216);  // pre-GEMM1 only
    unsigned short* Win_b   = (unsigned short*)(base + 20971520);  // pre-GEMM1 only (ends 37748736)
    unsigned short* u_b     = (unsigned short*)(base + 16777216);  // 8.39MB (xproj_fused onward)
    float*          part16  = (float*)(base + 25165824);           // 16.78MB split-K partials
    unsigned short* Slocb   = (unsigned short*)(base + 25165824);  // 8.39MB bf16 (aliases part16)
    float*          opart   = (float*)(base + 25165824);           // 16.78MB (aliases Slocb)
    unsigned short* dlt_b   = (unsigned short*)(base + 41943040);  // 8.39MB
    unsigned short* y_b     = (unsigned short*)(base + 50331648);  // 8.39MB
    float*          projt   = (float*)(base + 58720256);           // 1.05MB (2048 x 128)
    unsigned short* projt_b = (unsigned short*)(base + 59768832);  // 0.52MB
    unsigned short* Wout_b  = (unsigned short*)(base + 60293120);  // 4.19MB
    unsigned short* Wx_b    = (unsigned short*)(base + 64487424);  // 0.52MB (128 x 2048)
    unsigned short* Wdt_b   = (unsigned short*)(base + 65011712);  // 0.26MB
    float*          sumd    = (float*)(base + 65273856);           // 1.05MB (128 x 2048)

    // 0. all bf16 conversions in one dispatch (1097728 8-elem units)
    cvt_all<<<4289, 256, 0, stream>>>(hidden, W_in, W_out, W_dt, W_x,
                                      hid_b, Win_b, Wout_b, Wdt_b, Wx_b);

    // 1. xz = hidden @ W_in^T  (2048 x 4096, K=1024) bf16 MFMA -> bf16 out
    gemm_bf16<128, 128, 1><<<dim3(32, 16, 1), 256, 0, stream>>>(
        hid_b, DMODEL, Win_b, DMODEL, xz_b, 4096, 0, DMODEL, DMODEL, nullptr);

    // 2+3. fused conv+silu + x-proj GEMM (split-K 16; also emits u_b), + reduce
    xproj_fused<<<dim3(1, 16, KSPLIT), 256, 0, stream>>>(
        xz_b, conv_w, conv_b, Wx_b, u_b, part16);
    reduce_part<<<SEQLEN * NPAD / 256, 256, 0, stream>>>(part16, projt, projt_b);

    // 4. delta = softplus(dt_lr @ W_dt^T + dt_bias) -> bf16  (2048 x 2048, K=64)
    gemm_bf16<128, 64, 2><<<dim3(32, 16, 1), 256, 0, stream>>>(
        projt_b, NPAD, Wdt_b, DTRANK, dlt_b, INNER, 0, DTRANK, DTRANK, dt_bias);

    // 5-7. chunked selective scan (CHUNK=16, bf16 state) + fused epilogue
    scan_phase1<<<dim3(INNER / 256, NCH), 256, 0, stream>>>(dlt_b, u_b, projt, A_log, Slocb, sumd);
    scan_phase2<<<(INNER * DSTATE) / 256, 256, 0, stream>>>(Slocb, sumd, A_log);
    scan_phase3<<<dim3(INNER / 256, NCH), 256, 0, stream>>>(dlt_b, u_b, projt, A_log,
                                                            Slocb, xz_b, D_skip, y_b);

    // 8. out = y @ W_out^T  (2048 x 1024, K=2048) bf16 MFMA, split-K 2 + combine
    gemm_bf16<128, 64, 0><<<dim3(16, 16, 2), 256, 0, stream>>>(
        y_b, INNER, Wout_b, INNER, opart, DMODEL, (long long)SEQLEN * DMODEL,
        INNER, INNER / 2, nullptr);
    reduce_out<<<SEQLEN * DMODEL / 1024, 256, 0, stream>>>(opart, out);
}